// Round 1
// baseline (378.153 us; speedup 1.0000x reference)
//
#include <hip/hip_runtime.h>

typedef __attribute__((ext_vector_type(8))) short bfrag;
typedef __attribute__((ext_vector_type(4))) float ffrag;
typedef __attribute__((ext_vector_type(8))) unsigned short us8;
typedef __attribute__((ext_vector_type(4))) unsigned short us4;
typedef __attribute__((ext_vector_type(2))) unsigned short us2;

#define DEVI static __device__ __forceinline__

DEVI unsigned short f2bf(float f){
  unsigned int u = __float_as_uint(f);
  u += 0x7fffu + ((u >> 16) & 1u);   // round-to-nearest-even
  return (unsigned short)(u >> 16);
}
// XOR swizzle in ushort units: granule = 8 bf16 (16B). Row-major tile,
// row stride 64 / 256 ushorts. Bijective per row; consistent write+read.
DEVI int swz64(int r, int c){ return ((r << 6) + c) ^ ((r & 7) << 3); }
DEVI int swz256(int r, int c){ return ((r << 8) + c) ^ ((r & 7) << 3); }

// ---------------- 1) GroupNorm stats -> per-(b,c) scale/shift ----------------
__global__ __launch_bounds__(256) void gn_stats(
    const float* __restrict__ x, const float* __restrict__ gw,
    const float* __restrict__ gb, float* __restrict__ ss){
  const int b = blockIdx.x >> 5, g = blockIdx.x & 31;
  const int t = threadIdx.x;
  const float4* base = (const float4*)(x + (((size_t)b * 256 + g * 8) << 12));
  float s = 0.f, q = 0.f;
  #pragma unroll
  for (int i = 0; i < 32; ++i){
    float4 v = base[i * 256 + t];
    s += v.x + v.y + v.z + v.w;
    q += v.x * v.x + v.y * v.y + v.z * v.z + v.w * v.w;
  }
  #pragma unroll
  for (int m = 32; m; m >>= 1){ s += __shfl_down(s, m); q += __shfl_down(q, m); }
  __shared__ float ps[4], pq[4];
  if ((t & 63) == 0){ ps[t >> 6] = s; pq[t >> 6] = q; }
  __syncthreads();
  if (t < 8){
    float S = ps[0] + ps[1] + ps[2] + ps[3];
    float Q = pq[0] + pq[1] + pq[2] + pq[3];
    float mean = S * (1.f / 32768.f);
    float var  = Q * (1.f / 32768.f) - mean * mean;
    float rstd = rsqrtf(var + 1e-5f);
    int c = g * 8 + t;
    float sc = gw[c] * rstd;
    ss[b * 256 + c] = sc;
    ss[1024 + b * 256 + c] = gb[c] - mean * sc;
  }
}

// ------- 2) normalize + transpose: xn_t[b][n][c] = bf16(x*scale+shift) -------
__global__ __launch_bounds__(256) void normalize_t(
    const float* __restrict__ x, const float* __restrict__ ss,
    unsigned short* __restrict__ xnt){
  const int n0 = blockIdx.x << 6, b = blockIdx.y;
  const int t = threadIdx.x;
  __shared__ unsigned short T[64 * 258];   // [n_local][c], pad 258 vs bank conflicts
  const float* xb = x + ((size_t)b << 20);
  const float* sc = ss + b * 256;
  const float* sh = ss + 1024 + b * 256;
  #pragma unroll 4
  for (int e = 0; e < 64; ++e){
    int idx = e * 256 + t;
    int c = idx >> 6, nl = idx & 63;           // c uniform per wave
    float v = xb[((size_t)c << 12) + n0 + nl]; // coalesced along n
    T[nl * 258 + c] = f2bf(v * sc[c] + sh[c]);
  }
  __syncthreads();
  unsigned short* dst = xnt + ((((size_t)b << 12) + n0) << 8);
  #pragma unroll 4
  for (int e = 0; e < 32; ++e){
    int idx = e * 256 + t;
    int nl = idx >> 7, c2 = (idx & 127) << 1;
    *(us2*)(dst + (nl << 8) + c2) = *(const us2*)&T[nl * 258 + c2];
  }
}

// ---- 3) QKV GEMM: qkv[o][n] = W[o][c] @ xn[c][n] + b; writes q_t,k_t,v ----
__global__ __launch_bounds__(256) void qkv_gemm(
    const unsigned short* __restrict__ xnt, const float* __restrict__ W,
    const float* __restrict__ bias, unsigned short* __restrict__ qt,
    unsigned short* __restrict__ kt, unsigned short* __restrict__ vt){
  const int n0 = blockIdx.x << 6, MT = blockIdx.y, b = blockIdx.z;
  const int t = threadIdx.x, l = t & 63, w = t >> 6;
  __shared__ __align__(16) unsigned short Al[64 * 256];  // [m][k] swizzled
  __shared__ __align__(16) unsigned short Bl[64 * 256];  // [n][k] swizzled
  const float* Arow = W + (size_t)(MT << 6) * 256;
  #pragma unroll
  for (int e = 0; e < 16; ++e){
    int fi = e * 256 + t;
    int m = fi >> 6, c4 = (fi & 63) << 2;
    float4 v = *(const float4*)(Arow + m * 256 + c4);
    us4 u; u[0] = f2bf(v.x); u[1] = f2bf(v.y); u[2] = f2bf(v.z); u[3] = f2bf(v.w);
    *(us4*)&Al[swz256(m, c4)] = u;
  }
  const us8* src = (const us8*)(xnt + ((((size_t)b << 12) + n0) << 8));
  #pragma unroll
  for (int e = 0; e < 8; ++e){
    int g = e * 256 + t;
    *(us8*)&Bl[swz256(g >> 5, (g & 31) << 3)] = src[g];
  }
  __syncthreads();
  ffrag acc[4] = {{0,0,0,0},{0,0,0,0},{0,0,0,0},{0,0,0,0}};
  #pragma unroll
  for (int kc = 0; kc < 8; ++kc){
    bfrag a = *(const bfrag*)&Al[swz256((w << 4) + (l & 15), (kc << 5) + ((l >> 4) << 3))];
    #pragma unroll
    for (int fc = 0; fc < 4; ++fc){
      bfrag bb = *(const bfrag*)&Bl[swz256((fc << 4) + (l & 15), (kc << 5) + ((l >> 4) << 3))];
      acc[fc] = __builtin_amdgcn_mfma_f32_16x16x32_bf16(a, bb, acc[fc], 0, 0, 0);
    }
  }
  const int which = MT >> 2, h = MT & 3;     // uniform per block
  const int d0 = (w << 4) + ((l >> 4) << 2);
  float bi[4];
  #pragma unroll
  for (int r = 0; r < 4; ++r) bi[r] = bias[(MT << 6) + d0 + r];
  #pragma unroll
  for (int fc = 0; fc < 4; ++fc){
    int n = n0 + (fc << 4) + (l & 15);
    if (which < 2){                 // q,k -> [b][h][n][d]
      unsigned short* dst = (which == 0 ? qt : kt) +
          (((size_t)(b * 4 + h)) << 18) + ((size_t)n << 6) + d0;
      us4 u;
      #pragma unroll
      for (int r = 0; r < 4; ++r) u[r] = f2bf(acc[fc][r] + bi[r]);
      *(us4*)dst = u;
    } else {                        // v -> [b][h][d][n]
      #pragma unroll
      for (int r = 0; r < 4; ++r)
        vt[((((size_t)(b * 4 + h)) << 6) + d0 + r) * 4096 + n] = f2bf(acc[fc][r] + bi[r]);
    }
  }
}

// ------------- 4) flash attention, QT=64 KT=64, 4 waves/block -------------
__global__ __launch_bounds__(256) void attn_kernel(
    const unsigned short* __restrict__ qt, const unsigned short* __restrict__ kt,
    const unsigned short* __restrict__ vt, unsigned short* __restrict__ at){
  const int q0 = blockIdx.x << 6, h = blockIdx.y, b = blockIdx.z;
  const int t = threadIdx.x, l = t & 63, w = t >> 6;
  const size_t bh = (size_t)b * 4 + h;
  __shared__ __align__(16) unsigned short Ql[4096];  // [q][d] swizzled
  __shared__ __align__(16) unsigned short Kl[4096];  // [k][d] swizzled
  __shared__ __align__(16) unsigned short Vl[4096];  // [d][k] swizzled
  __shared__ __align__(16) unsigned short Pl[4096];  // per-wave [16][64] swizzled
  __shared__ float Ol[64 * 65];
  const us8* qsrc = (const us8*)(qt + (bh << 18) + ((size_t)q0 << 6));
  #pragma unroll
  for (int e = 0; e < 2; ++e){
    int g = e * 256 + t;
    *(us8*)&Ql[swz64(g >> 3, (g & 7) << 3)] = qsrc[g];
  }
  __syncthreads();
  bfrag aq0 = *(const bfrag*)&Ql[swz64((w << 4) + (l & 15), (l >> 4) << 3)];
  bfrag aq1 = *(const bfrag*)&Ql[swz64((w << 4) + (l & 15), 32 + ((l >> 4) << 3))];
  ffrag acc[4] = {{0,0,0,0},{0,0,0,0},{0,0,0,0},{0,0,0,0}};
  float m[4], lsum[4];
  #pragma unroll
  for (int r = 0; r < 4; ++r){ m[r] = -1e30f; lsum[r] = 0.f; }
  const unsigned short* kbase = kt + (bh << 18);
  const unsigned short* vbase = vt + (bh << 18);
  for (int kti = 0; kti < 64; ++kti){
    const us8* ksrc = (const us8*)(kbase + ((size_t)kti << 12));
    #pragma unroll
    for (int e = 0; e < 2; ++e){
      int g = e * 256 + t;
      *(us8*)&Kl[swz64(g >> 3, (g & 7) << 3)] = ksrc[g];
    }
    #pragma unroll
    for (int e = 0; e < 2; ++e){
      int g = e * 256 + t;
      int r = g >> 3, gc = (g & 7) << 3;
      *(us8*)&Vl[swz64(r, gc)] = *(const us8*)(vbase + ((size_t)r << 12) + (kti << 6) + gc);
    }
    __syncthreads();
    // S = (Q^T K) * scale ; wave w owns q-rows w*16..+15
    ffrag s[4];
    #pragma unroll
    for (int fc = 0; fc < 4; ++fc){
      bfrag b0 = *(const bfrag*)&Kl[swz64((fc << 4) + (l & 15), (l >> 4) << 3)];
      bfrag b1 = *(const bfrag*)&Kl[swz64((fc << 4) + (l & 15), 32 + ((l >> 4) << 3))];
      ffrag z = {0,0,0,0};
      z = __builtin_amdgcn_mfma_f32_16x16x32_bf16(aq0, b0, z, 0, 0, 0);
      z = __builtin_amdgcn_mfma_f32_16x16x32_bf16(aq1, b1, z, 0, 0, 0);
      #pragma unroll
      for (int r = 0; r < 4; ++r) s[fc][r] = z[r] * 0.125f;
    }
    // online softmax: row = (l>>4)*4+r, 16 lanes (l&15) hold the k-slice
    float pm[4];
    #pragma unroll
    for (int r = 0; r < 4; ++r)
      pm[r] = fmaxf(fmaxf(s[0][r], s[1][r]), fmaxf(s[2][r], s[3][r]));
    #pragma unroll
    for (int xm = 1; xm <= 8; xm <<= 1){
      #pragma unroll
      for (int r = 0; r < 4; ++r) pm[r] = fmaxf(pm[r], __shfl_xor(pm[r], xm));
    }
    float al[4], ps[4];
    #pragma unroll
    for (int r = 0; r < 4; ++r){
      float mn = fmaxf(m[r], pm[r]);
      al[r] = __expf(m[r] - mn);
      m[r] = mn;
      ps[r] = 0.f;
    }
    #pragma unroll
    for (int fc = 0; fc < 4; ++fc){
      #pragma unroll
      for (int r = 0; r < 4; ++r){
        float p = __expf(s[fc][r] - m[r]);
        s[fc][r] = p;
        ps[r] += p;
      }
    }
    #pragma unroll
    for (int xm = 1; xm <= 8; xm <<= 1){
      #pragma unroll
      for (int r = 0; r < 4; ++r) ps[r] += __shfl_xor(ps[r], xm);
    }
    #pragma unroll
    for (int r = 0; r < 4; ++r) lsum[r] = lsum[r] * al[r] + ps[r];
    #pragma unroll
    for (int fc = 0; fc < 4; ++fc){
      #pragma unroll
      for (int r = 0; r < 4; ++r) acc[fc][r] *= al[r];
    }
    // P -> per-wave LDS (re-shape S-frag -> A-frag layout)
    const int pb = w << 10;
    #pragma unroll
    for (int fc = 0; fc < 4; ++fc){
      #pragma unroll
      for (int r = 0; r < 4; ++r)
        Pl[pb + swz64(((l >> 4) << 2) + r, (fc << 4) + (l & 15))] = f2bf(s[fc][r]);
    }
    bfrag ap0 = *(const bfrag*)&Pl[pb + swz64(l & 15, (l >> 4) << 3)];
    bfrag ap1 = *(const bfrag*)&Pl[pb + swz64(l & 15, 32 + ((l >> 4) << 3))];
    #pragma unroll
    for (int fc = 0; fc < 4; ++fc){
      bfrag v0 = *(const bfrag*)&Vl[swz64((fc << 4) + (l & 15), (l >> 4) << 3)];
      bfrag v1 = *(const bfrag*)&Vl[swz64((fc << 4) + (l & 15), 32 + ((l >> 4) << 3))];
      acc[fc] = __builtin_amdgcn_mfma_f32_16x16x32_bf16(ap0, v0, acc[fc], 0, 0, 0);
      acc[fc] = __builtin_amdgcn_mfma_f32_16x16x32_bf16(ap1, v1, acc[fc], 0, 0, 0);
    }
    __syncthreads();
  }
  float inv[4];
  #pragma unroll
  for (int r = 0; r < 4; ++r) inv[r] = 1.f / lsum[r];
  #pragma unroll
  for (int fc = 0; fc < 4; ++fc){
    #pragma unroll
    for (int r = 0; r < 4; ++r)
      Ol[((w << 4) + ((l >> 4) << 2) + r) * 65 + (fc << 4) + (l & 15)] = acc[fc][r] * inv[r];
  }
  __syncthreads();
  #pragma unroll
  for (int e = 0; e < 16; ++e){
    int idx = e * 256 + t;
    int qq = idx >> 6, d = idx & 63;
    at[((((size_t)b << 12) + q0 + qq) << 8) + (h << 6) + d] = f2bf(Ol[qq * 65 + d]);
  }
}

// -------- 5) proj GEMM + bias + residual: out = x + W@attn_out + b --------
__global__ __launch_bounds__(256) void proj_gemm(
    const unsigned short* __restrict__ at, const float* __restrict__ W,
    const float* __restrict__ bias, const float* __restrict__ x,
    float* __restrict__ out){
  const int n0 = blockIdx.x << 6, MT = blockIdx.y, b = blockIdx.z;
  const int t = threadIdx.x, l = t & 63, w = t >> 6;
  __shared__ __align__(16) unsigned short Al[64 * 256];
  __shared__ __align__(16) unsigned short Bl[64 * 256];
  const float* Arow = W + (size_t)(MT << 6) * 256;
  #pragma unroll
  for (int e = 0; e < 16; ++e){
    int fi = e * 256 + t;
    int m = fi >> 6, c4 = (fi & 63) << 2;
    float4 v = *(const float4*)(Arow + m * 256 + c4);
    us4 u; u[0] = f2bf(v.x); u[1] = f2bf(v.y); u[2] = f2bf(v.z); u[3] = f2bf(v.w);
    *(us4*)&Al[swz256(m, c4)] = u;
  }
  const us8* src = (const us8*)(at + ((((size_t)b << 12) + n0) << 8));
  #pragma unroll
  for (int e = 0; e < 8; ++e){
    int g = e * 256 + t;
    *(us8*)&Bl[swz256(g >> 5, (g & 31) << 3)] = src[g];
  }
  __syncthreads();
  ffrag acc[4] = {{0,0,0,0},{0,0,0,0},{0,0,0,0},{0,0,0,0}};
  #pragma unroll
  for (int kc = 0; kc < 8; ++kc){
    bfrag a = *(const bfrag*)&Al[swz256((w << 4) + (l & 15), (kc << 5) + ((l >> 4) << 3))];
    #pragma unroll
    for (int fc = 0; fc < 4; ++fc){
      bfrag bb = *(const bfrag*)&Bl[swz256((fc << 4) + (l & 15), (kc << 5) + ((l >> 4) << 3))];
      acc[fc] = __builtin_amdgcn_mfma_f32_16x16x32_bf16(a, bb, acc[fc], 0, 0, 0);
    }
  }
  const int co = (MT << 6) + (w << 4) + ((l >> 4) << 2);
  #pragma unroll
  for (int fc = 0; fc < 4; ++fc){
    int n = n0 + (fc << 4) + (l & 15);
    #pragma unroll
    for (int r = 0; r < 4; ++r){
      size_t o = (((size_t)b * 256 + co + r) << 12) + n;
      out[o] = acc[fc][r] + bias[co + r] + x[o];
    }
  }
}

extern "C" void kernel_launch(void* const* d_in, const int* in_sizes, int n_in,
                              void* d_out, int out_size, void* d_ws, size_t ws_size,
                              hipStream_t stream){
  const float* x    = (const float*)d_in[0];
  const float* gw   = (const float*)d_in[1];
  const float* gb   = (const float*)d_in[2];
  const float* qkvw = (const float*)d_in[3];
  const float* qkvb = (const float*)d_in[4];
  const float* pw   = (const float*)d_in[5];
  const float* pb   = (const float*)d_in[6];
  float* out = (float*)d_out;

  float* ss = (float*)d_ws;                                   // 2*1024 f32
  unsigned short* xnt = (unsigned short*)((char*)d_ws + 16384);
  unsigned short* qt  = xnt + (size_t)4 * 4096 * 256;
  unsigned short* kt  = qt  + (size_t)16 * 4096 * 64;
  unsigned short* vt  = kt  + (size_t)16 * 4096 * 64;
  unsigned short* at  = vt  + (size_t)16 * 4096 * 64;

  gn_stats   <<<128, 256, 0, stream>>>(x, gw, gb, ss);
  normalize_t<<<dim3(64, 4), 256, 0, stream>>>(x, ss, xnt);
  qkv_gemm   <<<dim3(64, 12, 4), 256, 0, stream>>>(xnt, qkvw, qkvb, qt, kt, vt);
  attn_kernel<<<dim3(64, 4, 4), 256, 0, stream>>>(qt, kt, vt, at);
  proj_gemm  <<<dim3(64, 4, 4), 256, 0, stream>>>(at, pw, pb, x, out);
}

// Round 2
// 205.364 us; speedup vs baseline: 1.8414x; 1.8414x over previous
//
#include <hip/hip_runtime.h>

typedef __attribute__((ext_vector_type(8))) short bfrag;
typedef __attribute__((ext_vector_type(4))) float ffrag;
typedef __attribute__((ext_vector_type(8))) unsigned short us8;
typedef __attribute__((ext_vector_type(4))) unsigned short us4;
typedef __attribute__((ext_vector_type(2))) unsigned short us2;

#define DEVI static __device__ __forceinline__

DEVI unsigned short f2bf(float f){
  unsigned int u = __float_as_uint(f);
  u += 0x7fffu + ((u >> 16) & 1u);   // round-to-nearest-even
  return (unsigned short)(u >> 16);
}
// XOR swizzle in ushort units: granule = 8 bf16 (16B). Row-major tile,
// row stride 64 / 256 ushorts. Bijective per row; consistent write+read.
DEVI int swz64(int r, int c){ return ((r << 6) + c) ^ ((r & 7) << 3); }
DEVI int swz256(int r, int c){ return ((r << 8) + c) ^ ((r & 7) << 3); }

// ---------------- 1) GroupNorm stats -> per-(b,c) scale/shift ----------------
__global__ __launch_bounds__(256) void gn_stats(
    const float* __restrict__ x, const float* __restrict__ gw,
    const float* __restrict__ gb, float* __restrict__ ss){
  const int b = blockIdx.x >> 5, g = blockIdx.x & 31;
  const int t = threadIdx.x;
  const float4* base = (const float4*)(x + (((size_t)b * 256 + g * 8) << 12));
  float s = 0.f, q = 0.f;
  #pragma unroll
  for (int i = 0; i < 32; ++i){
    float4 v = base[i * 256 + t];
    s += v.x + v.y + v.z + v.w;
    q += v.x * v.x + v.y * v.y + v.z * v.z + v.w * v.w;
  }
  #pragma unroll
  for (int m = 32; m; m >>= 1){ s += __shfl_down(s, m); q += __shfl_down(q, m); }
  __shared__ float ps[4], pq[4];
  if ((t & 63) == 0){ ps[t >> 6] = s; pq[t >> 6] = q; }
  __syncthreads();
  if (t < 8){
    float S = ps[0] + ps[1] + ps[2] + ps[3];
    float Q = pq[0] + pq[1] + pq[2] + pq[3];
    float mean = S * (1.f / 32768.f);
    float var  = Q * (1.f / 32768.f) - mean * mean;
    float rstd = rsqrtf(var + 1e-5f);
    int c = g * 8 + t;
    float sc = gw[c] * rstd;
    ss[b * 256 + c] = sc;
    ss[1024 + b * 256 + c] = gb[c] - mean * sc;
  }
}

// ------- 2) normalize + transpose: xn_t[b][n][c] = bf16(x*scale+shift) -------
__global__ __launch_bounds__(256) void normalize_t(
    const float* __restrict__ x, const float* __restrict__ ss,
    unsigned short* __restrict__ xnt){
  const int n0 = blockIdx.x << 6, b = blockIdx.y;
  const int t = threadIdx.x;
  __shared__ unsigned short T[64 * 258];
  const float* xb = x + ((size_t)b << 20);
  const float* sc = ss + b * 256;
  const float* sh = ss + 1024 + b * 256;
  #pragma unroll 4
  for (int e = 0; e < 64; ++e){
    int idx = e * 256 + t;
    int c = idx >> 6, nl = idx & 63;
    float v = xb[((size_t)c << 12) + n0 + nl];
    T[nl * 258 + c] = f2bf(v * sc[c] + sh[c]);
  }
  __syncthreads();
  unsigned short* dst = xnt + ((((size_t)b << 12) + n0) << 8);
  #pragma unroll 4
  for (int e = 0; e < 32; ++e){
    int idx = e * 256 + t;
    int nl = idx >> 7, c2 = (idx & 127) << 1;
    *(us2*)(dst + (nl << 8) + c2) = *(const us2*)&T[nl * 258 + c2];
  }
}

// ---- 3) QKV GEMM: qkv[o][n] = W[o][c] @ xn[c][n] + b; writes q_t,k_t,v ----
//      q is pre-scaled by hd^-0.5 = 0.125 (folded out of the attn inner loop)
__global__ __launch_bounds__(256) void qkv_gemm(
    const unsigned short* __restrict__ xnt, const float* __restrict__ W,
    const float* __restrict__ bias, unsigned short* __restrict__ qt,
    unsigned short* __restrict__ kt, unsigned short* __restrict__ vt){
  const int n0 = blockIdx.x << 6, MT = blockIdx.y, b = blockIdx.z;
  const int t = threadIdx.x, l = t & 63, w = t >> 6;
  __shared__ __align__(16) unsigned short Al[64 * 256];  // [m][k] swizzled
  __shared__ __align__(16) unsigned short Bl[64 * 256];  // [n][k] swizzled
  const float* Arow = W + (size_t)(MT << 6) * 256;
  #pragma unroll
  for (int e = 0; e < 16; ++e){
    int fi = e * 256 + t;
    int m = fi >> 6, c4 = (fi & 63) << 2;
    float4 v = *(const float4*)(Arow + m * 256 + c4);
    us4 u; u[0] = f2bf(v.x); u[1] = f2bf(v.y); u[2] = f2bf(v.z); u[3] = f2bf(v.w);
    *(us4*)&Al[swz256(m, c4)] = u;
  }
  const us8* src = (const us8*)(xnt + ((((size_t)b << 12) + n0) << 8));
  #pragma unroll
  for (int e = 0; e < 8; ++e){
    int g = e * 256 + t;
    *(us8*)&Bl[swz256(g >> 5, (g & 31) << 3)] = src[g];
  }
  __syncthreads();
  ffrag acc[4] = {{0,0,0,0},{0,0,0,0},{0,0,0,0},{0,0,0,0}};
  #pragma unroll
  for (int kc = 0; kc < 8; ++kc){
    bfrag a = *(const bfrag*)&Al[swz256((w << 4) + (l & 15), (kc << 5) + ((l >> 4) << 3))];
    #pragma unroll
    for (int fc = 0; fc < 4; ++fc){
      bfrag bb = *(const bfrag*)&Bl[swz256((fc << 4) + (l & 15), (kc << 5) + ((l >> 4) << 3))];
      acc[fc] = __builtin_amdgcn_mfma_f32_16x16x32_bf16(a, bb, acc[fc], 0, 0, 0);
    }
  }
  const int which = MT >> 2, h = MT & 3;
  const int d0 = (w << 4) + ((l >> 4) << 2);
  float bi[4];
  #pragma unroll
  for (int r = 0; r < 4; ++r) bi[r] = bias[(MT << 6) + d0 + r];
  #pragma unroll
  for (int fc = 0; fc < 4; ++fc){
    int n = n0 + (fc << 4) + (l & 15);
    if (which < 2){                 // q,k -> [b][h][n][d]
      unsigned short* dst = (which == 0 ? qt : kt) +
          (((size_t)(b * 4 + h)) << 18) + ((size_t)n << 6) + d0;
      const float qs = (which == 0) ? 0.125f : 1.0f;
      us4 u;
      #pragma unroll
      for (int r = 0; r < 4; ++r) u[r] = f2bf((acc[fc][r] + bi[r]) * qs);
      *(us4*)dst = u;
    } else {                        // v -> [b][h][d][n]
      #pragma unroll
      for (int r = 0; r < 4; ++r)
        vt[((((size_t)(b * 4 + h)) << 6) + d0 + r) * 4096 + n] = f2bf(acc[fc][r] + bi[r]);
    }
  }
}

// ------------- 4) flash attention, QT=64 KT=64, 4 waves/block -------------
// LDS 32 KB (5 blocks/CU by LDS); T14 reg-prefetch of next K/V tile;
// row-sum via MFMA(ones); defer-max; setprio around MFMA clusters.
__global__ __launch_bounds__(256, 4) void attn_kernel(
    const unsigned short* __restrict__ qt, const unsigned short* __restrict__ kt,
    const unsigned short* __restrict__ vt, unsigned short* __restrict__ at){
  const int q0 = blockIdx.x << 6, h = blockIdx.y, b = blockIdx.z;
  const int t = threadIdx.x, l = t & 63, w = t >> 6;
  const size_t bh = (size_t)b * 4 + h;
  __shared__ __align__(16) unsigned short Ql[4096];  // [q][d] swizzled
  __shared__ __align__(16) unsigned short Kl[4096];  // [k][d] swizzled
  __shared__ __align__(16) unsigned short Vl[4096];  // [d][k] swizzled
  __shared__ __align__(16) unsigned short Pl[4096];  // per-wave [16][64] swizzled
  const unsigned short* kbase = kt + (bh << 18);
  const unsigned short* vbase = vt + (bh << 18);

  // Q -> LDS
  const us8* qsrc = (const us8*)(qt + (bh << 18) + ((size_t)q0 << 6));
  *(us8*)&Ql[swz64(t >> 3, (t & 7) << 3)] = qsrc[t];
  *(us8*)&Ql[swz64((256 + t) >> 3, (t & 7) << 3)] = qsrc[256 + t];

  const int krow0 = t >> 3, krow1 = 32 + (t >> 3), kcol = (t & 7) << 3;
  us8 rk0, rk1, rv0, rv1;
  // tile 0
  {
    const unsigned short* kp = kbase;
    rk0 = *(const us8*)(kp + (krow0 << 6) + kcol);
    rk1 = *(const us8*)(kp + (krow1 << 6) + kcol);
    rv0 = *(const us8*)(vbase + ((size_t)krow0 << 12) + kcol);
    rv1 = *(const us8*)(vbase + ((size_t)krow1 << 12) + kcol);
  }
  *(us8*)&Kl[swz64(krow0, kcol)] = rk0;
  *(us8*)&Kl[swz64(krow1, kcol)] = rk1;
  *(us8*)&Vl[swz64(krow0, kcol)] = rv0;
  *(us8*)&Vl[swz64(krow1, kcol)] = rv1;
  __syncthreads();

  bfrag aq0 = *(const bfrag*)&Ql[swz64((w << 4) + (l & 15), (l >> 4) << 3)];
  bfrag aq1 = *(const bfrag*)&Ql[swz64((w << 4) + (l & 15), 32 + ((l >> 4) << 3))];

  ffrag acc[4] = {{0,0,0,0},{0,0,0,0},{0,0,0,0},{0,0,0,0}};
  float m[4], lsum[4];
  #pragma unroll
  for (int r = 0; r < 4; ++r){ m[r] = -1e30f; lsum[r] = 0.f; }
  bfrag ones;
  #pragma unroll
  for (int j = 0; j < 8; ++j) ones[j] = (short)0x3F80;   // bf16 1.0

  for (int kti = 0; kti < 64; ++kti){
    // T14: issue next tile's loads now; consumed after the post-compute barrier
    if (kti < 63){
      const unsigned short* kp = kbase + ((size_t)(kti + 1) << 12);
      rk0 = *(const us8*)(kp + (krow0 << 6) + kcol);
      rk1 = *(const us8*)(kp + (krow1 << 6) + kcol);
      rv0 = *(const us8*)(vbase + ((size_t)krow0 << 12) + ((kti + 1) << 6) + kcol);
      rv1 = *(const us8*)(vbase + ((size_t)krow1 << 12) + ((kti + 1) << 6) + kcol);
    }
    // S = Q K^T (Q pre-scaled); wave w owns q-rows w*16..+15
    ffrag s[4];
    __builtin_amdgcn_s_setprio(1);
    #pragma unroll
    for (int fc = 0; fc < 4; ++fc){
      bfrag b0 = *(const bfrag*)&Kl[swz64((fc << 4) + (l & 15), (l >> 4) << 3)];
      bfrag b1 = *(const bfrag*)&Kl[swz64((fc << 4) + (l & 15), 32 + ((l >> 4) << 3))];
      ffrag z = {0,0,0,0};
      z = __builtin_amdgcn_mfma_f32_16x16x32_bf16(aq0, b0, z, 0, 0, 0);
      z = __builtin_amdgcn_mfma_f32_16x16x32_bf16(aq1, b1, z, 0, 0, 0);
      s[fc] = z;
    }
    __builtin_amdgcn_s_setprio(0);
    // tile max per q-row (row = (l>>4)*4+r, 16 lanes l&15 hold k-slices)
    float pm[4];
    #pragma unroll
    for (int r = 0; r < 4; ++r)
      pm[r] = fmaxf(fmaxf(s[0][r], s[1][r]), fmaxf(s[2][r], s[3][r]));
    #pragma unroll
    for (int xm = 1; xm <= 8; xm <<= 1){
      #pragma unroll
      for (int r = 0; r < 4; ++r) pm[r] = fmaxf(pm[r], __shfl_xor(pm[r], xm));
    }
    // defer-max: only rescale when the max actually grew past THR=8
    if (!__all(pm[0] <= m[0] + 8.f && pm[1] <= m[1] + 8.f &&
               pm[2] <= m[2] + 8.f && pm[3] <= m[3] + 8.f)){
      #pragma unroll
      for (int r = 0; r < 4; ++r){
        float mn = fmaxf(m[r], pm[r]);
        float al = __expf(m[r] - mn);
        m[r] = mn;
        lsum[r] *= al;
        #pragma unroll
        for (int fc = 0; fc < 4; ++fc) acc[fc][r] *= al;
      }
    }
    // P = exp(S - m) -> per-wave LDS (S-frag -> A-frag reshape)
    const int pb = w << 10;
    #pragma unroll
    for (int fc = 0; fc < 4; ++fc){
      #pragma unroll
      for (int r = 0; r < 4; ++r)
        Pl[pb + swz64(((l >> 4) << 2) + r, (fc << 4) + (l & 15))] =
            f2bf(__expf(s[fc][r] - m[r]));
    }
    bfrag ap0 = *(const bfrag*)&Pl[pb + swz64(l & 15, (l >> 4) << 3)];
    bfrag ap1 = *(const bfrag*)&Pl[pb + swz64(l & 15, 32 + ((l >> 4) << 3))];
    // row-sum of P via MFMA against all-ones B (lands in same row layout)
    __builtin_amdgcn_s_setprio(1);
    ffrag zs = {0,0,0,0};
    zs = __builtin_amdgcn_mfma_f32_16x16x32_bf16(ap0, ones, zs, 0, 0, 0);
    zs = __builtin_amdgcn_mfma_f32_16x16x32_bf16(ap1, ones, zs, 0, 0, 0);
    #pragma unroll
    for (int fc = 0; fc < 4; ++fc){
      bfrag v0 = *(const bfrag*)&Vl[swz64((fc << 4) + (l & 15), (l >> 4) << 3)];
      bfrag v1 = *(const bfrag*)&Vl[swz64((fc << 4) + (l & 15), 32 + ((l >> 4) << 3))];
      acc[fc] = __builtin_amdgcn_mfma_f32_16x16x32_bf16(ap0, v0, acc[fc], 0, 0, 0);
      acc[fc] = __builtin_amdgcn_mfma_f32_16x16x32_bf16(ap1, v1, acc[fc], 0, 0, 0);
    }
    __builtin_amdgcn_s_setprio(0);
    #pragma unroll
    for (int r = 0; r < 4; ++r) lsum[r] += zs[r];
    if (kti < 63){
      __syncthreads();              // all waves done reading Kl/Vl
      *(us8*)&Kl[swz64(krow0, kcol)] = rk0;
      *(us8*)&Kl[swz64(krow1, kcol)] = rk1;
      *(us8*)&Vl[swz64(krow0, kcol)] = rv0;
      *(us8*)&Vl[swz64(krow1, kcol)] = rv1;
      __syncthreads();              // next tile visible
    }
  }
  // epilogue: normalize, reshape via per-wave Pl, coalesced store
  float inv[4];
  #pragma unroll
  for (int r = 0; r < 4; ++r) inv[r] = 1.f / lsum[r];
  const int pb = w << 10;
  #pragma unroll
  for (int fc = 0; fc < 4; ++fc){
    #pragma unroll
    for (int r = 0; r < 4; ++r)
      Pl[pb + swz64(((l >> 4) << 2) + r, (fc << 4) + (l & 15))] =
          f2bf(acc[fc][r] * inv[r]);
  }
  unsigned short* dst = at + ((((size_t)b << 12) + q0 + (w << 4)) << 8) + (h << 6);
  #pragma unroll
  for (int e = 0; e < 2; ++e){
    int g = (e << 6) + l;
    int row = g >> 3, col = (g & 7) << 3;
    *(us8*)(dst + ((size_t)row << 8) + col) = *(const us8*)&Pl[pb + swz64(row, col)];
  }
}

// -------- 5) proj GEMM + bias + residual: out = x + W@attn_out + b --------
__global__ __launch_bounds__(256) void proj_gemm(
    const unsigned short* __restrict__ at, const float* __restrict__ W,
    const float* __restrict__ bias, const float* __restrict__ x,
    float* __restrict__ out){
  const int n0 = blockIdx.x << 6, MT = blockIdx.y, b = blockIdx.z;
  const int t = threadIdx.x, l = t & 63, w = t >> 6;
  __shared__ __align__(16) unsigned short Al[64 * 256];
  __shared__ __align__(16) unsigned short Bl[64 * 256];
  const float* Arow = W + (size_t)(MT << 6) * 256;
  #pragma unroll
  for (int e = 0; e < 16; ++e){
    int fi = e * 256 + t;
    int m = fi >> 6, c4 = (fi & 63) << 2;
    float4 v = *(const float4*)(Arow + m * 256 + c4);
    us4 u; u[0] = f2bf(v.x); u[1] = f2bf(v.y); u[2] = f2bf(v.z); u[3] = f2bf(v.w);
    *(us4*)&Al[swz256(m, c4)] = u;
  }
  const us8* src = (const us8*)(at + ((((size_t)b << 12) + n0) << 8));
  #pragma unroll
  for (int e = 0; e < 8; ++e){
    int g = e * 256 + t;
    *(us8*)&Bl[swz256(g >> 5, (g & 31) << 3)] = src[g];
  }
  __syncthreads();
  ffrag acc[4] = {{0,0,0,0},{0,0,0,0},{0,0,0,0},{0,0,0,0}};
  #pragma unroll
  for (int kc = 0; kc < 8; ++kc){
    bfrag a = *(const bfrag*)&Al[swz256((w << 4) + (l & 15), (kc << 5) + ((l >> 4) << 3))];
    #pragma unroll
    for (int fc = 0; fc < 4; ++fc){
      bfrag bb = *(const bfrag*)&Bl[swz256((fc << 4) + (l & 15), (kc << 5) + ((l >> 4) << 3))];
      acc[fc] = __builtin_amdgcn_mfma_f32_16x16x32_bf16(a, bb, acc[fc], 0, 0, 0);
    }
  }
  const int co = (MT << 6) + (w << 4) + ((l >> 4) << 2);
  #pragma unroll
  for (int fc = 0; fc < 4; ++fc){
    int n = n0 + (fc << 4) + (l & 15);
    #pragma unroll
    for (int r = 0; r < 4; ++r){
      size_t o = (((size_t)b * 256 + co + r) << 12) + n;
      out[o] = acc[fc][r] + bias[co + r] + x[o];
    }
  }
}

extern "C" void kernel_launch(void* const* d_in, const int* in_sizes, int n_in,
                              void* d_out, int out_size, void* d_ws, size_t ws_size,
                              hipStream_t stream){
  const float* x    = (const float*)d_in[0];
  const float* gw   = (const float*)d_in[1];
  const float* gb   = (const float*)d_in[2];
  const float* qkvw = (const float*)d_in[3];
  const float* qkvb = (const float*)d_in[4];
  const float* pw   = (const float*)d_in[5];
  const float* pb   = (const float*)d_in[6];
  float* out = (float*)d_out;

  float* ss = (float*)d_ws;
  unsigned short* xnt = (unsigned short*)((char*)d_ws + 16384);
  unsigned short* qt  = xnt + (size_t)4 * 4096 * 256;
  unsigned short* kt  = qt  + (size_t)16 * 4096 * 64;
  unsigned short* vt  = kt  + (size_t)16 * 4096 * 64;
  unsigned short* at  = vt  + (size_t)16 * 4096 * 64;

  gn_stats   <<<128, 256, 0, stream>>>(x, gw, gb, ss);
  normalize_t<<<dim3(64, 4), 256, 0, stream>>>(x, ss, xnt);
  qkv_gemm   <<<dim3(64, 12, 4), 256, 0, stream>>>(xnt, qkvw, qkvb, qt, kt, vt);
  attn_kernel<<<dim3(64, 4, 4), 256, 0, stream>>>(qt, kt, vt, at);
  proj_gemm  <<<dim3(64, 4, 4), 256, 0, stream>>>(at, pw, pb, x, out);
}

// Round 3
// 169.683 us; speedup vs baseline: 2.2286x; 1.2103x over previous
//
#include <hip/hip_runtime.h>

typedef __attribute__((ext_vector_type(8))) short bfrag;
typedef __attribute__((ext_vector_type(4))) float ffrag;
typedef __attribute__((ext_vector_type(8))) unsigned short us8;
typedef __attribute__((ext_vector_type(4))) unsigned short us4;
typedef __attribute__((ext_vector_type(2))) unsigned short us2;

#define DEVI static __device__ __forceinline__

DEVI unsigned short f2bf(float f){
  unsigned int u = __float_as_uint(f);
  u += 0x7fffu + ((u >> 16) & 1u);   // round-to-nearest-even
  return (unsigned short)(u >> 16);
}
DEVI float fexp2(float x){ float r; asm("v_exp_f32 %0, %1" : "=v"(r) : "v"(x)); return r; }
// XOR swizzle in ushort units: granule = 8 bf16 (16B). Row-major tile,
// row stride 64 / 256 ushorts. Bijective per row; consistent write+read.
DEVI int swz64(int r, int c){ return ((r << 6) + c) ^ ((r & 7) << 3); }
DEVI int swz256(int r, int c){ return ((r << 8) + c) ^ ((r & 7) << 3); }

// ---------------- 1) GroupNorm stats -> per-(b,c) scale/shift ----------------
__global__ __launch_bounds__(256) void gn_stats(
    const float* __restrict__ x, const float* __restrict__ gw,
    const float* __restrict__ gb, float* __restrict__ ss){
  const int b = blockIdx.x >> 5, g = blockIdx.x & 31;
  const int t = threadIdx.x;
  const float4* base = (const float4*)(x + (((size_t)b * 256 + g * 8) << 12));
  float s = 0.f, q = 0.f;
  #pragma unroll
  for (int i = 0; i < 32; ++i){
    float4 v = base[i * 256 + t];
    s += v.x + v.y + v.z + v.w;
    q += v.x * v.x + v.y * v.y + v.z * v.z + v.w * v.w;
  }
  #pragma unroll
  for (int m = 32; m; m >>= 1){ s += __shfl_down(s, m); q += __shfl_down(q, m); }
  __shared__ float ps[4], pq[4];
  if ((t & 63) == 0){ ps[t >> 6] = s; pq[t >> 6] = q; }
  __syncthreads();
  if (t < 8){
    float S = ps[0] + ps[1] + ps[2] + ps[3];
    float Q = pq[0] + pq[1] + pq[2] + pq[3];
    float mean = S * (1.f / 32768.f);
    float var  = Q * (1.f / 32768.f) - mean * mean;
    float rstd = rsqrtf(var + 1e-5f);
    int c = g * 8 + t;
    float sc = gw[c] * rstd;
    ss[b * 256 + c] = sc;
    ss[1024 + b * 256 + c] = gb[c] - mean * sc;
  }
}

// ------- 2) normalize + transpose: xn_t[b][n][c] = bf16(x*scale+shift) -------
__global__ __launch_bounds__(256) void normalize_t(
    const float* __restrict__ x, const float* __restrict__ ss,
    unsigned short* __restrict__ xnt){
  const int n0 = blockIdx.x << 6, b = blockIdx.y;
  const int t = threadIdx.x;
  __shared__ unsigned short T[64 * 258];
  const float* xb = x + ((size_t)b << 20);
  const float* sc = ss + b * 256;
  const float* sh = ss + 1024 + b * 256;
  #pragma unroll 4
  for (int e = 0; e < 64; ++e){
    int idx = e * 256 + t;
    int c = idx >> 6, nl = idx & 63;
    float v = xb[((size_t)c << 12) + n0 + nl];
    T[nl * 258 + c] = f2bf(v * sc[c] + sh[c]);
  }
  __syncthreads();
  unsigned short* dst = xnt + ((((size_t)b << 12) + n0) << 8);
  #pragma unroll 4
  for (int e = 0; e < 32; ++e){
    int idx = e * 256 + t;
    int nl = idx >> 7, c2 = (idx & 127) << 1;
    *(us2*)(dst + (nl << 8) + c2) = *(const us2*)&T[nl * 258 + c2];
  }
}

// ---- 3) QKV GEMM: qkv[o][n] = W[o][c] @ xn[c][n] + b; writes q_t,k_t,v ----
//      q is pre-scaled by hd^-0.5 * log2(e) (softmax runs in exp2 domain)
__global__ __launch_bounds__(256) void qkv_gemm(
    const unsigned short* __restrict__ xnt, const float* __restrict__ W,
    const float* __restrict__ bias, unsigned short* __restrict__ qt,
    unsigned short* __restrict__ kt, unsigned short* __restrict__ vt){
  const int n0 = blockIdx.x << 6, MT = blockIdx.y, b = blockIdx.z;
  const int t = threadIdx.x, l = t & 63, w = t >> 6;
  __shared__ __align__(16) unsigned short Al[64 * 256];  // [m][k] swizzled
  __shared__ __align__(16) unsigned short Bl[64 * 256];  // [n][k] swizzled
  const float* Arow = W + (size_t)(MT << 6) * 256;
  #pragma unroll
  for (int e = 0; e < 16; ++e){
    int fi = e * 256 + t;
    int m = fi >> 6, c4 = (fi & 63) << 2;
    float4 v = *(const float4*)(Arow + m * 256 + c4);
    us4 u; u[0] = f2bf(v.x); u[1] = f2bf(v.y); u[2] = f2bf(v.z); u[3] = f2bf(v.w);
    *(us4*)&Al[swz256(m, c4)] = u;
  }
  const us8* src = (const us8*)(xnt + ((((size_t)b << 12) + n0) << 8));
  #pragma unroll
  for (int e = 0; e < 8; ++e){
    int g = e * 256 + t;
    *(us8*)&Bl[swz256(g >> 5, (g & 31) << 3)] = src[g];
  }
  __syncthreads();
  ffrag acc[4] = {{0,0,0,0},{0,0,0,0},{0,0,0,0},{0,0,0,0}};
  #pragma unroll
  for (int kc = 0; kc < 8; ++kc){
    bfrag a = *(const bfrag*)&Al[swz256((w << 4) + (l & 15), (kc << 5) + ((l >> 4) << 3))];
    #pragma unroll
    for (int fc = 0; fc < 4; ++fc){
      bfrag bb = *(const bfrag*)&Bl[swz256((fc << 4) + (l & 15), (kc << 5) + ((l >> 4) << 3))];
      acc[fc] = __builtin_amdgcn_mfma_f32_16x16x32_bf16(a, bb, acc[fc], 0, 0, 0);
    }
  }
  const int which = MT >> 2, h = MT & 3;
  const int d0 = (w << 4) + ((l >> 4) << 2);
  float bi[4];
  #pragma unroll
  for (int r = 0; r < 4; ++r) bi[r] = bias[(MT << 6) + d0 + r];
  #pragma unroll
  for (int fc = 0; fc < 4; ++fc){
    int n = n0 + (fc << 4) + (l & 15);
    if (which < 2){                 // q,k -> [b][h][n][d]
      unsigned short* dst = (which == 0 ? qt : kt) +
          (((size_t)(b * 4 + h)) << 18) + ((size_t)n << 6) + d0;
      const float qs = (which == 0) ? 0.125f * 1.44269504f : 1.0f;
      us4 u;
      #pragma unroll
      for (int r = 0; r < 4; ++r) u[r] = f2bf((acc[fc][r] + bi[r]) * qs);
      *(us4*)dst = u;
    } else {                        // v -> [b][h][d][n]
      #pragma unroll
      for (int r = 0; r < 4; ++r)
        vt[((((size_t)(b * 4 + h)) << 6) + d0 + r) * 4096 + n] = f2bf(acc[fc][r] + bi[r]);
    }
  }
}

// ------------- 4) flash attention, QT=64 KT=64, 4 waves/block -------------
// LDS 40 KB, double-buffered K/V (Q buffer reused as K-buf1): ONE barrier/iter.
// Softmax in exp2 domain; lane-local defer-max check (no shuffles common path).
__global__ __launch_bounds__(256, 4) void attn_kernel(
    const unsigned short* __restrict__ qt, const unsigned short* __restrict__ kt,
    const unsigned short* __restrict__ vt, unsigned short* __restrict__ at){
  const int q0 = blockIdx.x << 6, h = blockIdx.y, b = blockIdx.z;
  const int t = threadIdx.x, l = t & 63, w = t >> 6;
  const size_t bh = (size_t)b * 4 + h;
  // [0]: Q then K-buf1 | [4096]: K-buf0 | [8192]: V-buf0 | [12288]: V-buf1
  // [16384]: per-wave P (1024 ushorts each)
  __shared__ __align__(16) unsigned short S[20480];
  const unsigned short* kbase = kt + (bh << 18);
  const unsigned short* vbase = vt + (bh << 18);

  const int row0 = t >> 3, row1 = 32 + (t >> 3), col8 = (t & 7) << 3;
  // stage Q (offset 0), K tile0 (4096), V tile0 (8192)
  const us8* qsrc = (const us8*)(qt + (bh << 18) + ((size_t)q0 << 6));
  *(us8*)&S[swz64(row0, col8)] = qsrc[t];
  *(us8*)&S[swz64(row1, col8)] = qsrc[256 + t];
  *(us8*)&S[4096 + swz64(row0, col8)] = *(const us8*)(kbase + (row0 << 6) + col8);
  *(us8*)&S[4096 + swz64(row1, col8)] = *(const us8*)(kbase + (row1 << 6) + col8);
  *(us8*)&S[8192 + swz64(row0, col8)] = *(const us8*)(vbase + ((size_t)row0 << 12) + col8);
  *(us8*)&S[8192 + swz64(row1, col8)] = *(const us8*)(vbase + ((size_t)row1 << 12) + col8);
  __syncthreads();
  bfrag aq0 = *(const bfrag*)&S[swz64((w << 4) + (l & 15), (l >> 4) << 3)];
  bfrag aq1 = *(const bfrag*)&S[swz64((w << 4) + (l & 15), 32 + ((l >> 4) << 3))];
  __syncthreads();   // Q reads done; region 0 free for K-buf1

  ffrag acc[4] = {{0,0,0,0},{0,0,0,0},{0,0,0,0},{0,0,0,0}};
  float m[4], lsum[4];
  #pragma unroll
  for (int r = 0; r < 4; ++r){ m[r] = -1e30f; lsum[r] = 0.f; }
  bfrag ones;
  #pragma unroll
  for (int j = 0; j < 8; ++j) ones[j] = (short)0x3F80;   // bf16 1.0
  const int pb = 16384 + (w << 10);

  us8 rk0, rk1, rv0, rv1;
  #pragma unroll 2
  for (int kti = 0; kti < 64; ++kti){
    const int kb = (kti & 1) ? 0 : 4096;        // read buffers this iter
    const int vb = (kti & 1) ? 12288 : 8192;
    // T14: issue next tile's global loads now; written to alt buffers later
    if (kti < 63){
      const unsigned short* kp = kbase + ((size_t)(kti + 1) << 12);
      rk0 = *(const us8*)(kp + (row0 << 6) + col8);
      rk1 = *(const us8*)(kp + (row1 << 6) + col8);
      rv0 = *(const us8*)(vbase + ((size_t)row0 << 12) + ((kti + 1) << 6) + col8);
      rv1 = *(const us8*)(vbase + ((size_t)row1 << 12) + ((kti + 1) << 6) + col8);
    }
    // S = Q K^T (Q pre-scaled to exp2 domain); wave w owns q-rows w*16..+15
    ffrag s[4];
    __builtin_amdgcn_s_setprio(1);
    #pragma unroll
    for (int fc = 0; fc < 4; ++fc){
      bfrag b0 = *(const bfrag*)&S[kb + swz64((fc << 4) + (l & 15), (l >> 4) << 3)];
      bfrag b1 = *(const bfrag*)&S[kb + swz64((fc << 4) + (l & 15), 32 + ((l >> 4) << 3))];
      ffrag z = {0,0,0,0};
      z = __builtin_amdgcn_mfma_f32_16x16x32_bf16(aq0, b0, z, 0, 0, 0);
      z = __builtin_amdgcn_mfma_f32_16x16x32_bf16(aq1, b1, z, 0, 0, 0);
      s[fc] = z;
    }
    __builtin_amdgcn_s_setprio(0);
    // lane-local max per q-row; __all over the wave covers all 16 k-lanes
    float lm[4];
    #pragma unroll
    for (int r = 0; r < 4; ++r)
      lm[r] = fmaxf(fmaxf(s[0][r], s[1][r]), fmaxf(s[2][r], s[3][r]));
    if (!__all(lm[0] <= m[0] + 8.f && lm[1] <= m[1] + 8.f &&
               lm[2] <= m[2] + 8.f && lm[3] <= m[3] + 8.f)){
      float pm[4];
      #pragma unroll
      for (int r = 0; r < 4; ++r) pm[r] = lm[r];
      #pragma unroll
      for (int xm = 1; xm <= 8; xm <<= 1){
        #pragma unroll
        for (int r = 0; r < 4; ++r) pm[r] = fmaxf(pm[r], __shfl_xor(pm[r], xm));
      }
      #pragma unroll
      for (int r = 0; r < 4; ++r){
        float mn = fmaxf(m[r], pm[r]);
        float al = fexp2(m[r] - mn);
        m[r] = mn;
        lsum[r] *= al;
        #pragma unroll
        for (int fc = 0; fc < 4; ++fc) acc[fc][r] *= al;
      }
    }
    // P = exp2(S - m) -> per-wave LDS (S-frag -> A-frag reshape)
    #pragma unroll
    for (int fc = 0; fc < 4; ++fc){
      #pragma unroll
      for (int r = 0; r < 4; ++r)
        S[pb + swz64(((l >> 4) << 2) + r, (fc << 4) + (l & 15))] =
            f2bf(fexp2(s[fc][r] - m[r]));
    }
    bfrag ap0 = *(const bfrag*)&S[pb + swz64(l & 15, (l >> 4) << 3)];
    bfrag ap1 = *(const bfrag*)&S[pb + swz64(l & 15, 32 + ((l >> 4) << 3))];
    // row-sum of P via MFMA against all-ones B (lands in same row layout)
    __builtin_amdgcn_s_setprio(1);
    ffrag zs = {0,0,0,0};
    zs = __builtin_amdgcn_mfma_f32_16x16x32_bf16(ap0, ones, zs, 0, 0, 0);
    zs = __builtin_amdgcn_mfma_f32_16x16x32_bf16(ap1, ones, zs, 0, 0, 0);
    #pragma unroll
    for (int fc = 0; fc < 4; ++fc){
      bfrag v0 = *(const bfrag*)&S[vb + swz64((fc << 4) + (l & 15), (l >> 4) << 3)];
      bfrag v1 = *(const bfrag*)&S[vb + swz64((fc << 4) + (l & 15), 32 + ((l >> 4) << 3))];
      acc[fc] = __builtin_amdgcn_mfma_f32_16x16x32_bf16(ap0, v0, acc[fc], 0, 0, 0);
      acc[fc] = __builtin_amdgcn_mfma_f32_16x16x32_bf16(ap1, v1, acc[fc], 0, 0, 0);
    }
    __builtin_amdgcn_s_setprio(0);
    #pragma unroll
    for (int r = 0; r < 4; ++r) lsum[r] += zs[r];
    if (kti < 63){
      // write next tile into the ALT buffers (read two iters ago -> safe),
      // then a single barrier publishes them and retires this iter's reads
      const int kb2 = (kti & 1) ? 4096 : 0;
      const int vb2 = (kti & 1) ? 8192 : 12288;
      *(us8*)&S[kb2 + swz64(row0, col8)] = rk0;
      *(us8*)&S[kb2 + swz64(row1, col8)] = rk1;
      *(us8*)&S[vb2 + swz64(row0, col8)] = rv0;
      *(us8*)&S[vb2 + swz64(row1, col8)] = rv1;
      __syncthreads();
    }
  }
  // epilogue: normalize, reshape via per-wave P region, coalesced store
  float inv[4];
  #pragma unroll
  for (int r = 0; r < 4; ++r) inv[r] = 1.f / lsum[r];
  #pragma unroll
  for (int fc = 0; fc < 4; ++fc){
    #pragma unroll
    for (int r = 0; r < 4; ++r)
      S[pb + swz64(((l >> 4) << 2) + r, (fc << 4) + (l & 15))] =
          f2bf(acc[fc][r] * inv[r]);
  }
  unsigned short* dst = at + ((((size_t)b << 12) + q0 + (w << 4)) << 8) + (h << 6);
  #pragma unroll
  for (int e = 0; e < 2; ++e){
    int g = (e << 6) + l;
    int row = g >> 3, col = (g & 7) << 3;
    *(us8*)(dst + ((size_t)row << 8) + col) = *(const us8*)&S[pb + swz64(row, col)];
  }
}

// -------- 5) proj GEMM + bias + residual: out = x + W@attn_out + b --------
__global__ __launch_bounds__(256) void proj_gemm(
    const unsigned short* __restrict__ at, const float* __restrict__ W,
    const float* __restrict__ bias, const float* __restrict__ x,
    float* __restrict__ out){
  const int n0 = blockIdx.x << 6, MT = blockIdx.y, b = blockIdx.z;
  const int t = threadIdx.x, l = t & 63, w = t >> 6;
  __shared__ __align__(16) unsigned short Al[64 * 256];
  __shared__ __align__(16) unsigned short Bl[64 * 256];
  const float* Arow = W + (size_t)(MT << 6) * 256;
  #pragma unroll
  for (int e = 0; e < 16; ++e){
    int fi = e * 256 + t;
    int m = fi >> 6, c4 = (fi & 63) << 2;
    float4 v = *(const float4*)(Arow + m * 256 + c4);
    us4 u; u[0] = f2bf(v.x); u[1] = f2bf(v.y); u[2] = f2bf(v.z); u[3] = f2bf(v.w);
    *(us4*)&Al[swz256(m, c4)] = u;
  }
  const us8* src = (const us8*)(at + ((((size_t)b << 12) + n0) << 8));
  #pragma unroll
  for (int e = 0; e < 8; ++e){
    int g = e * 256 + t;
    *(us8*)&Bl[swz256(g >> 5, (g & 31) << 3)] = src[g];
  }
  __syncthreads();
  ffrag acc[4] = {{0,0,0,0},{0,0,0,0},{0,0,0,0},{0,0,0,0}};
  #pragma unroll
  for (int kc = 0; kc < 8; ++kc){
    bfrag a = *(const bfrag*)&Al[swz256((w << 4) + (l & 15), (kc << 5) + ((l >> 4) << 3))];
    #pragma unroll
    for (int fc = 0; fc < 4; ++fc){
      bfrag bb = *(const bfrag*)&Bl[swz256((fc << 4) + (l & 15), (kc << 5) + ((l >> 4) << 3))];
      acc[fc] = __builtin_amdgcn_mfma_f32_16x16x32_bf16(a, bb, acc[fc], 0, 0, 0);
    }
  }
  const int co = (MT << 6) + (w << 4) + ((l >> 4) << 2);
  #pragma unroll
  for (int fc = 0; fc < 4; ++fc){
    int n = n0 + (fc << 4) + (l & 15);
    #pragma unroll
    for (int r = 0; r < 4; ++r){
      size_t o = (((size_t)b * 256 + co + r) << 12) + n;
      out[o] = acc[fc][r] + bias[co + r] + x[o];
    }
  }
}

extern "C" void kernel_launch(void* const* d_in, const int* in_sizes, int n_in,
                              void* d_out, int out_size, void* d_ws, size_t ws_size,
                              hipStream_t stream){
  const float* x    = (const float*)d_in[0];
  const float* gw   = (const float*)d_in[1];
  const float* gb   = (const float*)d_in[2];
  const float* qkvw = (const float*)d_in[3];
  const float* qkvb = (const float*)d_in[4];
  const float* pw   = (const float*)d_in[5];
  const float* pb   = (const float*)d_in[6];
  float* out = (float*)d_out;

  float* ss = (float*)d_ws;
  unsigned short* xnt = (unsigned short*)((char*)d_ws + 16384);
  unsigned short* qt  = xnt + (size_t)4 * 4096 * 256;
  unsigned short* kt  = qt  + (size_t)16 * 4096 * 64;
  unsigned short* vt  = kt  + (size_t)16 * 4096 * 64;
  unsigned short* at  = vt  + (size_t)16 * 4096 * 64;

  gn_stats   <<<128, 256, 0, stream>>>(x, gw, gb, ss);
  normalize_t<<<dim3(64, 4), 256, 0, stream>>>(x, ss, xnt);
  qkv_gemm   <<<dim3(64, 12, 4), 256, 0, stream>>>(xnt, qkvw, qkvb, qt, kt, vt);
  attn_kernel<<<dim3(64, 4, 4), 256, 0, stream>>>(qt, kt, vt, at);
  proj_gemm  <<<dim3(64, 4, 4), 256, 0, stream>>>(at, pw, pb, x, out);
}

// Round 4
// 149.053 us; speedup vs baseline: 2.5370x; 1.1384x over previous
//
#include <hip/hip_runtime.h>

typedef __attribute__((ext_vector_type(8))) short bfrag;
typedef __attribute__((ext_vector_type(4))) float ffrag;
typedef __attribute__((ext_vector_type(8))) unsigned short us8;
typedef __attribute__((ext_vector_type(4))) unsigned short us4;
typedef __attribute__((ext_vector_type(2))) unsigned short us2;

#define DEVI static __device__ __forceinline__

DEVI unsigned short f2bf(float f){
  unsigned int u = __float_as_uint(f);
  u += 0x7fffu + ((u >> 16) & 1u);   // round-to-nearest-even
  return (unsigned short)(u >> 16);
}
DEVI float fexp2(float x){ float r; asm("v_exp_f32 %0, %1" : "=v"(r) : "v"(x)); return r; }
DEVI unsigned int cvt_pk_bf16(float lo, float hi){
  unsigned int r;
  asm("v_cvt_pk_bf16_f32 %0, %1, %2" : "=v"(r) : "v"(lo), "v"(hi));
  return r;
}
// XOR swizzle in ushort units: granule = 8 bf16 (16B). Row-major tile,
// row stride 64 / 256 ushorts. Bijective per row; consistent write+read.
DEVI int swz64(int r, int c){ return ((r << 6) + c) ^ ((r & 7) << 3); }
DEVI int swz256(int r, int c){ return ((r << 8) + c) ^ ((r & 7) << 3); }

// ---------------- 1) GroupNorm stats -> per-(b,c) scale/shift ----------------
__global__ __launch_bounds__(256) void gn_stats(
    const float* __restrict__ x, const float* __restrict__ gw,
    const float* __restrict__ gb, float* __restrict__ ss){
  const int b = blockIdx.x >> 5, g = blockIdx.x & 31;
  const int t = threadIdx.x;
  const float4* base = (const float4*)(x + (((size_t)b * 256 + g * 8) << 12));
  float s = 0.f, q = 0.f;
  #pragma unroll
  for (int i = 0; i < 32; ++i){
    float4 v = base[i * 256 + t];
    s += v.x + v.y + v.z + v.w;
    q += v.x * v.x + v.y * v.y + v.z * v.z + v.w * v.w;
  }
  #pragma unroll
  for (int m = 32; m; m >>= 1){ s += __shfl_down(s, m); q += __shfl_down(q, m); }
  __shared__ float ps[4], pq[4];
  if ((t & 63) == 0){ ps[t >> 6] = s; pq[t >> 6] = q; }
  __syncthreads();
  if (t < 8){
    float S = ps[0] + ps[1] + ps[2] + ps[3];
    float Q = pq[0] + pq[1] + pq[2] + pq[3];
    float mean = S * (1.f / 32768.f);
    float var  = Q * (1.f / 32768.f) - mean * mean;
    float rstd = rsqrtf(var + 1e-5f);
    int c = g * 8 + t;
    float sc = gw[c] * rstd;
    ss[b * 256 + c] = sc;
    ss[1024 + b * 256 + c] = gb[c] - mean * sc;
  }
}

// ------- 2) normalize + transpose: xn_t[b][n][c] = bf16(x*scale+shift) -------
__global__ __launch_bounds__(256) void normalize_t(
    const float* __restrict__ x, const float* __restrict__ ss,
    unsigned short* __restrict__ xnt){
  const int n0 = blockIdx.x << 6, b = blockIdx.y;
  const int t = threadIdx.x;
  __shared__ unsigned short T[64 * 258];
  const float* xb = x + ((size_t)b << 20);
  const float* sc = ss + b * 256;
  const float* sh = ss + 1024 + b * 256;
  #pragma unroll 4
  for (int e = 0; e < 64; ++e){
    int idx = e * 256 + t;
    int c = idx >> 6, nl = idx & 63;
    float v = xb[((size_t)c << 12) + n0 + nl];
    T[nl * 258 + c] = f2bf(v * sc[c] + sh[c]);
  }
  __syncthreads();
  unsigned short* dst = xnt + ((((size_t)b << 12) + n0) << 8);
  #pragma unroll 4
  for (int e = 0; e < 32; ++e){
    int idx = e * 256 + t;
    int nl = idx >> 7, c2 = (idx & 127) << 1;
    *(us2*)(dst + (nl << 8) + c2) = *(const us2*)&T[nl * 258 + c2];
  }
}

// ---- 3) QKV GEMM: qkv[o][n] = W[o][c] @ xn[c][n] + b; writes q_t,k_t,v ----
//      q is pre-scaled by hd^-0.5 * log2(e) (softmax runs in exp2 domain)
__global__ __launch_bounds__(256) void qkv_gemm(
    const unsigned short* __restrict__ xnt, const float* __restrict__ W,
    const float* __restrict__ bias, unsigned short* __restrict__ qt,
    unsigned short* __restrict__ kt, unsigned short* __restrict__ vt){
  const int n0 = blockIdx.x << 6, MT = blockIdx.y, b = blockIdx.z;
  const int t = threadIdx.x, l = t & 63, w = t >> 6;
  __shared__ __align__(16) unsigned short Al[64 * 256];  // [m][k] swizzled
  __shared__ __align__(16) unsigned short Bl[64 * 256];  // [n][k] swizzled
  const float* Arow = W + (size_t)(MT << 6) * 256;
  #pragma unroll
  for (int e = 0; e < 16; ++e){
    int fi = e * 256 + t;
    int m = fi >> 6, c4 = (fi & 63) << 2;
    float4 v = *(const float4*)(Arow + m * 256 + c4);
    us4 u; u[0] = f2bf(v.x); u[1] = f2bf(v.y); u[2] = f2bf(v.z); u[3] = f2bf(v.w);
    *(us4*)&Al[swz256(m, c4)] = u;
  }
  const us8* src = (const us8*)(xnt + ((((size_t)b << 12) + n0) << 8));
  #pragma unroll
  for (int e = 0; e < 8; ++e){
    int g = e * 256 + t;
    *(us8*)&Bl[swz256(g >> 5, (g & 31) << 3)] = src[g];
  }
  __syncthreads();
  ffrag acc[4] = {{0,0,0,0},{0,0,0,0},{0,0,0,0},{0,0,0,0}};
  #pragma unroll
  for (int kc = 0; kc < 8; ++kc){
    bfrag a = *(const bfrag*)&Al[swz256((w << 4) + (l & 15), (kc << 5) + ((l >> 4) << 3))];
    #pragma unroll
    for (int fc = 0; fc < 4; ++fc){
      bfrag bb = *(const bfrag*)&Bl[swz256((fc << 4) + (l & 15), (kc << 5) + ((l >> 4) << 3))];
      acc[fc] = __builtin_amdgcn_mfma_f32_16x16x32_bf16(a, bb, acc[fc], 0, 0, 0);
    }
  }
  const int which = MT >> 2, h = MT & 3;
  const int d0 = (w << 4) + ((l >> 4) << 2);
  float bi[4];
  #pragma unroll
  for (int r = 0; r < 4; ++r) bi[r] = bias[(MT << 6) + d0 + r];
  #pragma unroll
  for (int fc = 0; fc < 4; ++fc){
    int n = n0 + (fc << 4) + (l & 15);
    if (which < 2){                 // q,k -> [b][h][n][d]
      unsigned short* dst = (which == 0 ? qt : kt) +
          (((size_t)(b * 4 + h)) << 18) + ((size_t)n << 6) + d0;
      const float qs = (which == 0) ? 0.125f * 1.44269504f : 1.0f;
      us4 u;
      #pragma unroll
      for (int r = 0; r < 4; ++r) u[r] = f2bf((acc[fc][r] + bi[r]) * qs);
      *(us4*)dst = u;
    } else {                        // v -> [b][h][d][n]
      #pragma unroll
      for (int r = 0; r < 4; ++r)
        vt[((((size_t)(b * 4 + h)) << 6) + d0 + r) * 4096 + n] = f2bf(acc[fc][r] + bi[r]);
    }
  }
}

// V staging: permuted k-order so the PV A-fragment is lane-local.
// actual k -> LDS col: f=k>>4, g=(k>>2)&3, r=k&3 : col = (f&2)*16 + g*8 + (f&1)*4 + r
DEVI void stage_v(unsigned short* Sb, int row, int c, const us8 v){
  const int f = c >> 1;
  const int b0 = ((f & 2) << 4) + ((((c << 1)) & 3) << 3) + ((f & 1) << 2);
  const int b1 = ((f & 2) << 4) + ((((c << 1) + 1) & 3) << 3) + ((f & 1) << 2);
  us4 lo; lo[0] = v[0]; lo[1] = v[1]; lo[2] = v[2]; lo[3] = v[3];
  us4 hi; hi[0] = v[4]; hi[1] = v[5]; hi[2] = v[6]; hi[3] = v[7];
  *(us4*)&Sb[swz64(row, b0)] = lo;
  *(us4*)&Sb[swz64(row, b1)] = hi;
}

// ------------- 4) flash attention, QT=64 KT=64, 4 waves/block -------------
// Swapped QK^T: S^T = mfma(K,Q) -> lane owns q=l&15, k lane-local.
// Softmax fully in-register (no P LDS round-trip); V k-permuted at staging.
// Double-buffered K/V, ONE barrier/iter; exp2-domain; lane-local defer-max.
__global__ __launch_bounds__(256, 4) void attn_kernel(
    const unsigned short* __restrict__ qt, const unsigned short* __restrict__ kt,
    const unsigned short* __restrict__ vt, unsigned short* __restrict__ at){
  const int q0 = blockIdx.x << 6, h = blockIdx.y, b = blockIdx.z;
  const int t = threadIdx.x, l = t & 63, w = t >> 6;
  const size_t bh = (size_t)b * 4 + h;
  // [0]: Q then K-buf1 | [4096]: K-buf0 | [8192]: V-buf0 | [12288]: V-buf1
  // [16384]: per-wave epilogue scratch (1024 ushorts each)
  __shared__ __align__(16) unsigned short S[20480];
  const unsigned short* kbase = kt + (bh << 18);
  const unsigned short* vbase = vt + (bh << 18);

  const int row0 = t >> 3, row1 = 32 + (t >> 3), c8 = t & 7, col8 = (t & 7) << 3;
  // stage Q (offset 0), K tile0 (4096), V tile0 (8192, permuted)
  const us8* qsrc = (const us8*)(qt + (bh << 18) + ((size_t)q0 << 6));
  *(us8*)&S[swz64(row0, col8)] = qsrc[t];
  *(us8*)&S[swz64(row1, col8)] = qsrc[256 + t];
  *(us8*)&S[4096 + swz64(row0, col8)] = *(const us8*)(kbase + (row0 << 6) + col8);
  *(us8*)&S[4096 + swz64(row1, col8)] = *(const us8*)(kbase + (row1 << 6) + col8);
  stage_v(&S[8192], row0, c8, *(const us8*)(vbase + ((size_t)row0 << 12) + col8));
  stage_v(&S[8192], row1, c8, *(const us8*)(vbase + ((size_t)row1 << 12) + col8));
  __syncthreads();
  // Q as B-operand: lane holds Q[q = w*16 + (l&15)][d = (l>>4)*8 + j]
  bfrag bq0 = *(const bfrag*)&S[swz64((w << 4) + (l & 15), (l >> 4) << 3)];
  bfrag bq1 = *(const bfrag*)&S[swz64((w << 4) + (l & 15), 32 + ((l >> 4) << 3))];
  __syncthreads();   // Q reads done; region 0 free for K-buf1

  ffrag acc[4] = {{0,0,0,0},{0,0,0,0},{0,0,0,0},{0,0,0,0}};
  float m = -1e30f, lsum = 0.f;

  us8 rk0, rk1, rv0, rv1;
  #pragma unroll 2
  for (int kti = 0; kti < 64; ++kti){
    const int kb = (kti & 1) ? 0 : 4096;        // read buffers this iter
    const int vb = (kti & 1) ? 12288 : 8192;
    // T14: issue next tile's global loads now; written to alt buffers later
    if (kti < 63){
      const unsigned short* kp = kbase + ((size_t)(kti + 1) << 12);
      rk0 = *(const us8*)(kp + (row0 << 6) + col8);
      rk1 = *(const us8*)(kp + (row1 << 6) + col8);
      rv0 = *(const us8*)(vbase + ((size_t)row0 << 12) + ((kti + 1) << 6) + col8);
      rv1 = *(const us8*)(vbase + ((size_t)row1 << 12) + ((kti + 1) << 6) + col8);
    }
    // S^T = K Q^T : lane holds s[fc][r] = S[q=l&15][k = fc*16 + 4*(l>>4) + r]
    ffrag s[4];
    __builtin_amdgcn_s_setprio(1);
    #pragma unroll
    for (int fc = 0; fc < 4; ++fc){
      bfrag ak0 = *(const bfrag*)&S[kb + swz64((fc << 4) + (l & 15), (l >> 4) << 3)];
      bfrag ak1 = *(const bfrag*)&S[kb + swz64((fc << 4) + (l & 15), 32 + ((l >> 4) << 3))];
      ffrag z = {0,0,0,0};
      z = __builtin_amdgcn_mfma_f32_16x16x32_bf16(ak0, bq0, z, 0, 0, 0);
      z = __builtin_amdgcn_mfma_f32_16x16x32_bf16(ak1, bq1, z, 0, 0, 0);
      s[fc] = z;
    }
    __builtin_amdgcn_s_setprio(0);
    // lane-local max over this lane's 16 k-slices (4 lanes/q cover all 64)
    float lm = fmaxf(fmaxf(s[0][0], s[0][1]), fmaxf(s[0][2], s[0][3]));
    #pragma unroll
    for (int fc = 1; fc < 4; ++fc)
      lm = fmaxf(lm, fmaxf(fmaxf(s[fc][0], s[fc][1]), fmaxf(s[fc][2], s[fc][3])));
    if (!__all(lm <= m + 8.f)){       // defer-max: rare path
      float pm = fmaxf(lm, __shfl_xor(lm, 16));
      pm = fmaxf(pm, __shfl_xor(pm, 32));
      float mn = fmaxf(m, pm);
      float al = fexp2(m - mn);
      m = mn;
      lsum *= al;
      float alT[4];
      #pragma unroll
      for (int r = 0; r < 4; ++r) alT[r] = __shfl(al, ((l >> 4) << 2) + r);
      #pragma unroll
      for (int fc = 0; fc < 4; ++fc){
        #pragma unroll
        for (int r = 0; r < 4; ++r) acc[fc][r] *= alT[r];
      }
    }
    // P = exp2(S - m), in-register; sum lane-locally; pack to A-frags
    float p[4][4];
    #pragma unroll
    for (int fc = 0; fc < 4; ++fc){
      #pragma unroll
      for (int r = 0; r < 4; ++r) p[fc][r] = fexp2(s[fc][r] - m);
    }
    float psum = 0.f;
    #pragma unroll
    for (int fc = 0; fc < 4; ++fc)
      psum += (p[fc][0] + p[fc][1]) + (p[fc][2] + p[fc][3]);
    lsum += psum;
    union { bfrag b; unsigned int u[4]; } A0, A1;
    A0.u[0] = cvt_pk_bf16(p[0][0], p[0][1]); A0.u[1] = cvt_pk_bf16(p[0][2], p[0][3]);
    A0.u[2] = cvt_pk_bf16(p[1][0], p[1][1]); A0.u[3] = cvt_pk_bf16(p[1][2], p[1][3]);
    A1.u[0] = cvt_pk_bf16(p[2][0], p[2][1]); A1.u[1] = cvt_pk_bf16(p[2][2], p[2][3]);
    A1.u[2] = cvt_pk_bf16(p[3][0], p[3][1]); A1.u[3] = cvt_pk_bf16(p[3][2], p[3][3]);
    // PV: V columns are k-permuted to match A-frag slot order
    __builtin_amdgcn_s_setprio(1);
    #pragma unroll
    for (int fc = 0; fc < 4; ++fc){
      bfrag v0 = *(const bfrag*)&S[vb + swz64((fc << 4) + (l & 15), (l >> 4) << 3)];
      bfrag v1 = *(const bfrag*)&S[vb + swz64((fc << 4) + (l & 15), 32 + ((l >> 4) << 3))];
      acc[fc] = __builtin_amdgcn_mfma_f32_16x16x32_bf16(A0.b, v0, acc[fc], 0, 0, 0);
      acc[fc] = __builtin_amdgcn_mfma_f32_16x16x32_bf16(A1.b, v1, acc[fc], 0, 0, 0);
    }
    __builtin_amdgcn_s_setprio(0);
    if (kti < 63){
      // write next tile into the ALT buffers, single barrier publishes
      const int kb2 = (kti & 1) ? 4096 : 0;
      const int vb2 = (kti & 1) ? 8192 : 12288;
      *(us8*)&S[kb2 + swz64(row0, col8)] = rk0;
      *(us8*)&S[kb2 + swz64(row1, col8)] = rk1;
      stage_v(&S[vb2], row0, c8, rv0);
      stage_v(&S[vb2], row1, c8, rv1);
      __syncthreads();
    }
  }
  // epilogue: lsum lives per q=l&15 (replicated across g after reduce)
  lsum += __shfl_xor(lsum, 16);
  lsum += __shfl_xor(lsum, 32);
  float inv = 1.f / lsum;
  float invT[4];
  #pragma unroll
  for (int r = 0; r < 4; ++r) invT[r] = __shfl(inv, ((l >> 4) << 2) + r);
  const int pb = 16384 + (w << 10);
  #pragma unroll
  for (int fc = 0; fc < 4; ++fc){
    #pragma unroll
    for (int r = 0; r < 4; ++r)
      S[pb + swz64(((l >> 4) << 2) + r, (fc << 4) + (l & 15))] =
          f2bf(acc[fc][r] * invT[r]);
  }
  unsigned short* dst = at + ((((size_t)b << 12) + q0 + (w << 4)) << 8) + (h << 6);
  #pragma unroll
  for (int e = 0; e < 2; ++e){
    int g = (e << 6) + l;
    int row = g >> 3, col = (g & 7) << 3;
    *(us8*)(dst + ((size_t)row << 8) + col) = *(const us8*)&S[pb + swz64(row, col)];
  }
}

// -------- 5) proj GEMM + bias + residual: out = x + W@attn_out + b --------
__global__ __launch_bounds__(256) void proj_gemm(
    const unsigned short* __restrict__ at, const float* __restrict__ W,
    const float* __restrict__ bias, const float* __restrict__ x,
    float* __restrict__ out){
  const int n0 = blockIdx.x << 6, MT = blockIdx.y, b = blockIdx.z;
  const int t = threadIdx.x, l = t & 63, w = t >> 6;
  __shared__ __align__(16) unsigned short Al[64 * 256];
  __shared__ __align__(16) unsigned short Bl[64 * 256];
  const float* Arow = W + (size_t)(MT << 6) * 256;
  #pragma unroll
  for (int e = 0; e < 16; ++e){
    int fi = e * 256 + t;
    int m = fi >> 6, c4 = (fi & 63) << 2;
    float4 v = *(const float4*)(Arow + m * 256 + c4);
    us4 u; u[0] = f2bf(v.x); u[1] = f2bf(v.y); u[2] = f2bf(v.z); u[3] = f2bf(v.w);
    *(us4*)&Al[swz256(m, c4)] = u;
  }
  const us8* src = (const us8*)(at + ((((size_t)b << 12) + n0) << 8));
  #pragma unroll
  for (int e = 0; e < 8; ++e){
    int g = e * 256 + t;
    *(us8*)&Bl[swz256(g >> 5, (g & 31) << 3)] = src[g];
  }
  __syncthreads();
  ffrag acc[4] = {{0,0,0,0},{0,0,0,0},{0,0,0,0},{0,0,0,0}};
  #pragma unroll
  for (int kc = 0; kc < 8; ++kc){
    bfrag a = *(const bfrag*)&Al[swz256((w << 4) + (l & 15), (kc << 5) + ((l >> 4) << 3))];
    #pragma unroll
    for (int fc = 0; fc < 4; ++fc){
      bfrag bb = *(const bfrag*)&Bl[swz256((fc << 4) + (l & 15), (kc << 5) + ((l >> 4) << 3))];
      acc[fc] = __builtin_amdgcn_mfma_f32_16x16x32_bf16(a, bb, acc[fc], 0, 0, 0);
    }
  }
  const int co = (MT << 6) + (w << 4) + ((l >> 4) << 2);
  #pragma unroll
  for (int fc = 0; fc < 4; ++fc){
    int n = n0 + (fc << 4) + (l & 15);
    #pragma unroll
    for (int r = 0; r < 4; ++r){
      size_t o = (((size_t)b * 256 + co + r) << 12) + n;
      out[o] = acc[fc][r] + bias[co + r] + x[o];
    }
  }
}

extern "C" void kernel_launch(void* const* d_in, const int* in_sizes, int n_in,
                              void* d_out, int out_size, void* d_ws, size_t ws_size,
                              hipStream_t stream){
  const float* x    = (const float*)d_in[0];
  const float* gw   = (const float*)d_in[1];
  const float* gb   = (const float*)d_in[2];
  const float* qkvw = (const float*)d_in[3];
  const float* qkvb = (const float*)d_in[4];
  const float* pw   = (const float*)d_in[5];
  const float* pb   = (const float*)d_in[6];
  float* out = (float*)d_out;

  float* ss = (float*)d_ws;
  unsigned short* xnt = (unsigned short*)((char*)d_ws + 16384);
  unsigned short* qt  = xnt + (size_t)4 * 4096 * 256;
  unsigned short* kt  = qt  + (size_t)16 * 4096 * 64;
  unsigned short* vt  = kt  + (size_t)16 * 4096 * 64;
  unsigned short* at  = vt  + (size_t)16 * 4096 * 64;

  gn_stats   <<<128, 256, 0, stream>>>(x, gw, gb, ss);
  normalize_t<<<dim3(64, 4), 256, 0, stream>>>(x, ss, xnt);
  qkv_gemm   <<<dim3(64, 12, 4), 256, 0, stream>>>(xnt, qkvw, qkvb, qt, kt, vt);
  attn_kernel<<<dim3(64, 4, 4), 256, 0, stream>>>(qt, kt, vt, at);
  proj_gemm  <<<dim3(64, 4, 4), 256, 0, stream>>>(at, pw, pb, x, out);
}

// Round 5
// 139.177 us; speedup vs baseline: 2.7171x; 1.0710x over previous
//
#include <hip/hip_runtime.h>

typedef __attribute__((ext_vector_type(8))) short bfrag;
typedef __attribute__((ext_vector_type(4))) float ffrag;
typedef __attribute__((ext_vector_type(8))) unsigned short us8;
typedef __attribute__((ext_vector_type(4))) unsigned short us4;
typedef __attribute__((ext_vector_type(2))) unsigned short us2;

#define DEVI static __device__ __forceinline__

DEVI unsigned short f2bf(float f){
  unsigned int u = __float_as_uint(f);
  u += 0x7fffu + ((u >> 16) & 1u);   // round-to-nearest-even
  return (unsigned short)(u >> 16);
}
DEVI float fexp2(float x){ float r; asm("v_exp_f32 %0, %1" : "=v"(r) : "v"(x)); return r; }
DEVI unsigned int cvt_pk_bf16(float lo, float hi){
  unsigned int r;
  asm("v_cvt_pk_bf16_f32 %0, %1, %2" : "=v"(r) : "v"(lo), "v"(hi));
  return r;
}
// XOR swizzle in ushort units: granule = 8 bf16 (16B). Row-major tile,
// row stride 64 / 256 ushorts. Bijective per row; consistent write+read.
DEVI int swz64(int r, int c){ return ((r << 6) + c) ^ ((r & 7) << 3); }
DEVI int swz256(int r, int c){ return ((r << 8) + c) ^ ((r & 7) << 3); }

// -------- 0) prep: W -> bf16 (q rows pre-scaled), bias prescale --------
__global__ __launch_bounds__(256) void prep_w(
    const float* __restrict__ qkvw, const float* __restrict__ qkvb,
    const float* __restrict__ pw, unsigned short* __restrict__ wq,
    unsigned short* __restrict__ wp, float* __restrict__ bq){
  const int i = blockIdx.x * 256 + threadIdx.x;      // grid 256 -> i < 65536
  const float qs = 0.125f * 1.44269504f;             // hd^-0.5 * log2(e)
  if (i < 49152){                                    // qkv_w: 196608/4 float4s
    float4 v = ((const float4*)qkvw)[i];
    float sc = (i < 16384) ? qs : 1.f;               // q rows (o<256)
    us4 u; u[0]=f2bf(v.x*sc); u[1]=f2bf(v.y*sc); u[2]=f2bf(v.z*sc); u[3]=f2bf(v.w*sc);
    ((us4*)wq)[i] = u;
  }
  if (i < 16384){                                    // proj_w: 65536/4
    float4 v = ((const float4*)pw)[i];
    us4 u; u[0]=f2bf(v.x); u[1]=f2bf(v.y); u[2]=f2bf(v.z); u[3]=f2bf(v.w);
    ((us4*)wp)[i] = u;
  }
  if (i < 768) bq[i] = qkvb[i] * (i < 256 ? qs : 1.f);
}

// ---------------- 1) GroupNorm stats -> per-(b,c) scale/shift ----------------
__global__ __launch_bounds__(256) void gn_stats(
    const float* __restrict__ x, const float* __restrict__ gw,
    const float* __restrict__ gb, float* __restrict__ ss){
  const int b = blockIdx.x >> 5, g = blockIdx.x & 31;
  const int t = threadIdx.x;
  const float4* base = (const float4*)(x + (((size_t)b * 256 + g * 8) << 12));
  float s = 0.f, q = 0.f;
  #pragma unroll
  for (int i = 0; i < 32; ++i){
    float4 v = base[i * 256 + t];
    s += v.x + v.y + v.z + v.w;
    q += v.x * v.x + v.y * v.y + v.z * v.z + v.w * v.w;
  }
  #pragma unroll
  for (int m = 32; m; m >>= 1){ s += __shfl_down(s, m); q += __shfl_down(q, m); }
  __shared__ float ps[4], pq[4];
  if ((t & 63) == 0){ ps[t >> 6] = s; pq[t >> 6] = q; }
  __syncthreads();
  if (t < 8){
    float S = ps[0] + ps[1] + ps[2] + ps[3];
    float Q = pq[0] + pq[1] + pq[2] + pq[3];
    float mean = S * (1.f / 32768.f);
    float var  = Q * (1.f / 32768.f) - mean * mean;
    float rstd = rsqrtf(var + 1e-5f);
    int c = g * 8 + t;
    float sc = gw[c] * rstd;
    ss[b * 256 + c] = sc;
    ss[1024 + b * 256 + c] = gb[c] - mean * sc;
  }
}

// ------- 2) normalize + transpose: xn_t[b][n][c] = bf16(x*scale+shift) -------
__global__ __launch_bounds__(256) void normalize_t(
    const float* __restrict__ x, const float* __restrict__ ss,
    unsigned short* __restrict__ xnt){
  const int n0 = blockIdx.x << 6, b = blockIdx.y;
  const int t = threadIdx.x;
  __shared__ unsigned short T[64 * 258];
  const float* xb = x + ((size_t)b << 20);
  const float* sc = ss + b * 256;
  const float* sh = ss + 1024 + b * 256;
  #pragma unroll 4
  for (int e = 0; e < 64; ++e){
    int idx = e * 256 + t;
    int c = idx >> 6, nl = idx & 63;
    float v = xb[((size_t)c << 12) + n0 + nl];
    T[nl * 258 + c] = f2bf(v * sc[c] + sh[c]);
  }
  __syncthreads();
  unsigned short* dst = xnt + ((((size_t)b << 12) + n0) << 8);
  #pragma unroll 4
  for (int e = 0; e < 32; ++e){
    int idx = e * 256 + t;
    int nl = idx >> 7, c2 = (idx & 127) << 1;
    *(us2*)(dst + (nl << 8) + c2) = *(const us2*)&T[nl * 258 + c2];
  }
}

// ---- 3) QKV GEMM: qkv[o][n] = W[o][c] @ xn[c][n] + b; writes q_t,k_t,v ----
//      W already bf16, q rows pre-scaled (exp2-domain softmax)
__global__ __launch_bounds__(256) void qkv_gemm(
    const unsigned short* __restrict__ xnt, const unsigned short* __restrict__ W,
    const float* __restrict__ bias, unsigned short* __restrict__ qt,
    unsigned short* __restrict__ kt, unsigned short* __restrict__ vt){
  const int n0 = blockIdx.x << 6, MT = blockIdx.y, b = blockIdx.z;
  const int t = threadIdx.x, l = t & 63, w = t >> 6;
  __shared__ __align__(16) unsigned short Al[64 * 256];  // [m][k] swizzled
  __shared__ __align__(16) unsigned short Bl[64 * 256];  // [n][k] swizzled
  const us8* Asrc = (const us8*)(W + (size_t)(MT << 6) * 256);
  #pragma unroll
  for (int e = 0; e < 8; ++e){
    int g = e * 256 + t;
    *(us8*)&Al[swz256(g >> 5, (g & 31) << 3)] = Asrc[g];
  }
  const us8* src = (const us8*)(xnt + ((((size_t)b << 12) + n0) << 8));
  #pragma unroll
  for (int e = 0; e < 8; ++e){
    int g = e * 256 + t;
    *(us8*)&Bl[swz256(g >> 5, (g & 31) << 3)] = src[g];
  }
  __syncthreads();
  ffrag acc[4] = {{0,0,0,0},{0,0,0,0},{0,0,0,0},{0,0,0,0}};
  #pragma unroll
  for (int kc = 0; kc < 8; ++kc){
    bfrag a = *(const bfrag*)&Al[swz256((w << 4) + (l & 15), (kc << 5) + ((l >> 4) << 3))];
    #pragma unroll
    for (int fc = 0; fc < 4; ++fc){
      bfrag bb = *(const bfrag*)&Bl[swz256((fc << 4) + (l & 15), (kc << 5) + ((l >> 4) << 3))];
      acc[fc] = __builtin_amdgcn_mfma_f32_16x16x32_bf16(a, bb, acc[fc], 0, 0, 0);
    }
  }
  const int which = MT >> 2, h = MT & 3;
  const int d0 = (w << 4) + ((l >> 4) << 2);
  float bi[4];
  #pragma unroll
  for (int r = 0; r < 4; ++r) bi[r] = bias[(MT << 6) + d0 + r];
  #pragma unroll
  for (int fc = 0; fc < 4; ++fc){
    int n = n0 + (fc << 4) + (l & 15);
    if (which < 2){                 // q,k -> [b][h][n][d]
      unsigned short* dst = (which == 0 ? qt : kt) +
          (((size_t)(b * 4 + h)) << 18) + ((size_t)n << 6) + d0;
      us4 u;
      #pragma unroll
      for (int r = 0; r < 4; ++r) u[r] = f2bf(acc[fc][r] + bi[r]);
      *(us4*)dst = u;
    } else {                        // v -> [b][h][d][n]
      #pragma unroll
      for (int r = 0; r < 4; ++r)
        vt[((((size_t)(b * 4 + h)) << 6) + d0 + r) * 4096 + n] = f2bf(acc[fc][r] + bi[r]);
    }
  }
}

// V staging: permuted k-order so the PV A-fragment is lane-local.
// actual k -> LDS col: f=k>>4, g=(k>>2)&3, r=k&3 : col = (f&2)*16 + g*8 + (f&1)*4 + r
DEVI void stage_v(unsigned short* Sb, int row, int c, const us8 v){
  const int f = c >> 1;
  const int b0 = ((f & 2) << 4) + ((((c << 1)) & 3) << 3) + ((f & 1) << 2);
  const int b1 = ((f & 2) << 4) + ((((c << 1) + 1) & 3) << 3) + ((f & 1) << 2);
  us4 lo; lo[0] = v[0]; lo[1] = v[1]; lo[2] = v[2]; lo[3] = v[3];
  us4 hi; hi[0] = v[4]; hi[1] = v[5]; hi[2] = v[6]; hi[3] = v[7];
  *(us4*)&Sb[swz64(row, b0)] = lo;
  *(us4*)&Sb[swz64(row, b1)] = hi;
}

// ------- 4) flash attention, 8 waves / 512 thr, 2 q-tiles share K/V -------
// Swapped QK^T (S^T = mfma(K,Q)): softmax fully in-register; V k-permuted.
// LDS 32 KB: K0/K1/V0/V1 4096-ushort regions; Q + epilogue alias onto them.
__global__ __launch_bounds__(512, 4) void attn_kernel(
    const unsigned short* __restrict__ qt, const unsigned short* __restrict__ kt,
    const unsigned short* __restrict__ vt, unsigned short* __restrict__ at){
  const int q0 = blockIdx.x << 7, h = blockIdx.y, b = blockIdx.z;
  const int t = threadIdx.x, l = t & 63, w = t >> 6;   // w in 0..7
  const size_t bh = (size_t)b * 4 + h;
  // [0]: Qa then K-buf1 | [4096]: K-buf0 | [8192]: V-buf0 | [12288]: Qb then V-buf1
  __shared__ __align__(16) unsigned short S[16384];
  const unsigned short* kbase = kt + (bh << 18);
  const unsigned short* vbase = vt + (bh << 18);

  const int row = t >> 3, c8 = t & 7, col8 = (t & 7) << 3;   // row 0..63
  const us8* qsrc = (const us8*)(qt + (bh << 18) + ((size_t)q0 << 6));
  *(us8*)&S[swz64(row, col8)] = qsrc[t];                       // Qa rows 0..63
  *(us8*)&S[12288 + swz64(row, col8)] = qsrc[512 + t];         // Qb rows 64..127
  *(us8*)&S[4096 + swz64(row, col8)] = *(const us8*)(kbase + (row << 6) + col8);
  stage_v(&S[8192], row, c8, *(const us8*)(vbase + ((size_t)row << 12) + col8));
  __syncthreads();
  // wave w: q rows q0 + (w>>2)*64 + (w&3)*16 ..+15 ; Q as B-operand
  const int qreg = (w >> 2) ? 12288 : 0;
  bfrag bq0 = *(const bfrag*)&S[qreg + swz64(((w & 3) << 4) + (l & 15), (l >> 4) << 3)];
  bfrag bq1 = *(const bfrag*)&S[qreg + swz64(((w & 3) << 4) + (l & 15), 32 + ((l >> 4) << 3))];
  __syncthreads();   // Q reads done; regions 0 / 12288 free for K1 / V1

  ffrag acc[4] = {{0,0,0,0},{0,0,0,0},{0,0,0,0},{0,0,0,0}};
  float m = -1e30f, lsum = 0.f;

  us8 rk, rv;
  #pragma unroll 2
  for (int kti = 0; kti < 64; ++kti){
    const int kb = (kti & 1) ? 0 : 4096;        // read buffers this iter
    const int vb = (kti & 1) ? 12288 : 8192;
    // T14: issue next tile's global loads now; written to alt buffers later
    if (kti < 63){
      rk = *(const us8*)(kbase + ((size_t)(kti + 1) << 12) + (row << 6) + col8);
      rv = *(const us8*)(vbase + ((size_t)row << 12) + ((kti + 1) << 6) + col8);
    }
    // S^T = K Q^T : lane holds s[fc][r] = S[q=l&15][k = fc*16 + 4*(l>>4) + r]
    ffrag s[4];
    __builtin_amdgcn_s_setprio(1);
    #pragma unroll
    for (int fc = 0; fc < 4; ++fc){
      bfrag ak0 = *(const bfrag*)&S[kb + swz64((fc << 4) + (l & 15), (l >> 4) << 3)];
      bfrag ak1 = *(const bfrag*)&S[kb + swz64((fc << 4) + (l & 15), 32 + ((l >> 4) << 3))];
      ffrag z = {0,0,0,0};
      z = __builtin_amdgcn_mfma_f32_16x16x32_bf16(ak0, bq0, z, 0, 0, 0);
      z = __builtin_amdgcn_mfma_f32_16x16x32_bf16(ak1, bq1, z, 0, 0, 0);
      s[fc] = z;
    }
    __builtin_amdgcn_s_setprio(0);
    // lane-local max over this lane's 16 k-slices (4 lanes/q cover all 64)
    float lm = fmaxf(fmaxf(s[0][0], s[0][1]), fmaxf(s[0][2], s[0][3]));
    #pragma unroll
    for (int fc = 1; fc < 4; ++fc)
      lm = fmaxf(lm, fmaxf(fmaxf(s[fc][0], s[fc][1]), fmaxf(s[fc][2], s[fc][3])));
    if (!__all(lm <= m + 8.f)){       // defer-max: rare path
      float pm = fmaxf(lm, __shfl_xor(lm, 16));
      pm = fmaxf(pm, __shfl_xor(pm, 32));
      float mn = fmaxf(m, pm);
      float al = fexp2(m - mn);
      m = mn;
      lsum *= al;
      float alT[4];
      #pragma unroll
      for (int r = 0; r < 4; ++r) alT[r] = __shfl(al, ((l >> 4) << 2) + r);
      #pragma unroll
      for (int fc = 0; fc < 4; ++fc){
        #pragma unroll
        for (int r = 0; r < 4; ++r) acc[fc][r] *= alT[r];
      }
    }
    // P = exp2(S - m), in-register; sum lane-locally; pack to A-frags
    float p[4][4];
    #pragma unroll
    for (int fc = 0; fc < 4; ++fc){
      #pragma unroll
      for (int r = 0; r < 4; ++r) p[fc][r] = fexp2(s[fc][r] - m);
    }
    float psum = 0.f;
    #pragma unroll
    for (int fc = 0; fc < 4; ++fc)
      psum += (p[fc][0] + p[fc][1]) + (p[fc][2] + p[fc][3]);
    lsum += psum;
    union { bfrag b; unsigned int u[4]; } A0, A1;
    A0.u[0] = cvt_pk_bf16(p[0][0], p[0][1]); A0.u[1] = cvt_pk_bf16(p[0][2], p[0][3]);
    A0.u[2] = cvt_pk_bf16(p[1][0], p[1][1]); A0.u[3] = cvt_pk_bf16(p[1][2], p[1][3]);
    A1.u[0] = cvt_pk_bf16(p[2][0], p[2][1]); A1.u[1] = cvt_pk_bf16(p[2][2], p[2][3]);
    A1.u[2] = cvt_pk_bf16(p[3][0], p[3][1]); A1.u[3] = cvt_pk_bf16(p[3][2], p[3][3]);
    // PV: V columns are k-permuted to match A-frag slot order
    __builtin_amdgcn_s_setprio(1);
    #pragma unroll
    for (int fc = 0; fc < 4; ++fc){
      bfrag v0 = *(const bfrag*)&S[vb + swz64((fc << 4) + (l & 15), (l >> 4) << 3)];
      bfrag v1 = *(const bfrag*)&S[vb + swz64((fc << 4) + (l & 15), 32 + ((l >> 4) << 3))];
      acc[fc] = __builtin_amdgcn_mfma_f32_16x16x32_bf16(A0.b, v0, acc[fc], 0, 0, 0);
      acc[fc] = __builtin_amdgcn_mfma_f32_16x16x32_bf16(A1.b, v1, acc[fc], 0, 0, 0);
    }
    __builtin_amdgcn_s_setprio(0);
    if (kti < 63){
      // write next tile into the ALT buffers, single barrier publishes
      const int kb2 = (kti & 1) ? 4096 : 0;
      const int vb2 = (kti & 1) ? 8192 : 12288;
      *(us8*)&S[kb2 + swz64(row, col8)] = rk;
      stage_v(&S[vb2], row, c8, rv);
      __syncthreads();
    }
  }
  __syncthreads();   // all K/V reads retired; LDS free for epilogue
  // epilogue: lsum lives per q=l&15 (replicated across groups after reduce)
  lsum += __shfl_xor(lsum, 16);
  lsum += __shfl_xor(lsum, 32);
  float inv = 1.f / lsum;
  float invT[4];
  #pragma unroll
  for (int r = 0; r < 4; ++r) invT[r] = __shfl(inv, ((l >> 4) << 2) + r);
  const int pb = w << 10;            // per-wave 1024-ushort scratch in [0..8191]
  #pragma unroll
  for (int fc = 0; fc < 4; ++fc){
    #pragma unroll
    for (int r = 0; r < 4; ++r)
      S[pb + swz64(((l >> 4) << 2) + r, (fc << 4) + (l & 15))] =
          f2bf(acc[fc][r] * invT[r]);
  }
  unsigned short* dst = at +
      ((((size_t)b << 12) + q0 + ((w >> 2) << 6) + ((w & 3) << 4)) << 8) + (h << 6);
  #pragma unroll
  for (int e = 0; e < 2; ++e){
    int g = (e << 6) + l;
    int rr = g >> 3, cc = (g & 7) << 3;
    *(us8*)(dst + ((size_t)rr << 8) + cc) = *(const us8*)&S[pb + swz64(rr, cc)];
  }
}

// -------- 5) proj GEMM + bias + residual: out = x + W@attn_out + b --------
__global__ __launch_bounds__(256) void proj_gemm(
    const unsigned short* __restrict__ at, const unsigned short* __restrict__ W,
    const float* __restrict__ bias, const float* __restrict__ x,
    float* __restrict__ out){
  const int n0 = blockIdx.x << 6, MT = blockIdx.y, b = blockIdx.z;
  const int t = threadIdx.x, l = t & 63, w = t >> 6;
  __shared__ __align__(16) unsigned short Al[64 * 256];
  __shared__ __align__(16) unsigned short Bl[64 * 256];
  const us8* Asrc = (const us8*)(W + (size_t)(MT << 6) * 256);
  #pragma unroll
  for (int e = 0; e < 8; ++e){
    int g = e * 256 + t;
    *(us8*)&Al[swz256(g >> 5, (g & 31) << 3)] = Asrc[g];
  }
  const us8* src = (const us8*)(at + ((((size_t)b << 12) + n0) << 8));
  #pragma unroll
  for (int e = 0; e < 8; ++e){
    int g = e * 256 + t;
    *(us8*)&Bl[swz256(g >> 5, (g & 31) << 3)] = src[g];
  }
  __syncthreads();
  ffrag acc[4] = {{0,0,0,0},{0,0,0,0},{0,0,0,0},{0,0,0,0}};
  #pragma unroll
  for (int kc = 0; kc < 8; ++kc){
    bfrag a = *(const bfrag*)&Al[swz256((w << 4) + (l & 15), (kc << 5) + ((l >> 4) << 3))];
    #pragma unroll
    for (int fc = 0; fc < 4; ++fc){
      bfrag bb = *(const bfrag*)&Bl[swz256((fc << 4) + (l & 15), (kc << 5) + ((l >> 4) << 3))];
      acc[fc] = __builtin_amdgcn_mfma_f32_16x16x32_bf16(a, bb, acc[fc], 0, 0, 0);
    }
  }
  const int co = (MT << 6) + (w << 4) + ((l >> 4) << 2);
  #pragma unroll
  for (int fc = 0; fc < 4; ++fc){
    int n = n0 + (fc << 4) + (l & 15);
    #pragma unroll
    for (int r = 0; r < 4; ++r){
      size_t o = (((size_t)b * 256 + co + r) << 12) + n;
      out[o] = acc[fc][r] + bias[co + r] + x[o];
    }
  }
}

extern "C" void kernel_launch(void* const* d_in, const int* in_sizes, int n_in,
                              void* d_out, int out_size, void* d_ws, size_t ws_size,
                              hipStream_t stream){
  const float* x    = (const float*)d_in[0];
  const float* gw   = (const float*)d_in[1];
  const float* gb   = (const float*)d_in[2];
  const float* qkvw = (const float*)d_in[3];
  const float* qkvb = (const float*)d_in[4];
  const float* pw   = (const float*)d_in[5];
  const float* pb   = (const float*)d_in[6];
  float* out = (float*)d_out;

  float* ss = (float*)d_ws;
  unsigned short* xnt = (unsigned short*)((char*)d_ws + 16384);
  unsigned short* qt  = xnt + (size_t)4 * 4096 * 256;
  unsigned short* kt  = qt  + (size_t)16 * 4096 * 64;
  unsigned short* vt  = kt  + (size_t)16 * 4096 * 64;
  unsigned short* at  = vt  + (size_t)16 * 4096 * 64;
  unsigned short* wq  = at  + (size_t)4 * 4096 * 256;
  unsigned short* wp  = wq  + (size_t)768 * 256;
  float*          bq  = (float*)(wp + (size_t)256 * 256);

  prep_w     <<<256, 256, 0, stream>>>(qkvw, qkvb, pw, wq, wp, bq);
  gn_stats   <<<128, 256, 0, stream>>>(x, gw, gb, ss);
  normalize_t<<<dim3(64, 4), 256, 0, stream>>>(x, ss, xnt);
  qkv_gemm   <<<dim3(64, 12, 4), 256, 0, stream>>>(xnt, wq, bq, qt, kt, vt);
  attn_kernel<<<dim3(32, 4, 4), 512, 0, stream>>>(qt, kt, vt, at);
  proj_gemm  <<<dim3(64, 4, 4), 256, 0, stream>>>(at, wp, pb, x, out);
}